// Round 6
// baseline (382.846 us; speedup 1.0000x reference)
//
#include <hip/hip_runtime.h>

#define N_NODES 100000
#define N_EDGES 3200000
#define N_FEAT  512
#define HID     16
#define N_CLASS 40

#define BSHIFT  9                      // 512 nodes per bucket
#define BMASK   ((1 << BSHIFT) - 1)
#define NB      196                    // ceil(100000 / 512)
#define CAP     18432                  // max edges/bucket (mean 16384, +16 sigma)
#define EPB     4096                   // edges per binning block

typedef __attribute__((ext_vector_type(8))) short bf16x8;
typedef __attribute__((ext_vector_type(4))) float f32x4;

// exact split: v == hi_f32 + lo_residual; hi = truncated-top-16 (exact),
// lo = bf16(v - hi) (residual <= 2^-8 |v|, its bf16 trunc err <= 2^-16 |v|)
__device__ inline short2 split_bf(float v) {
    const unsigned u = __float_as_uint(v);
    const short hi = (short)(u >> 16);
    const float hf = __uint_as_float(u & 0xFFFF0000u);
    const short lo = (short)(__float_as_uint(v - hf) >> 16);
    return make_short2(hi, lo);
}

// ============================== Stage 1 (MFMA) ==============================
// xn = rownorm(relu(x @ W1^T + b1)), norm = ||row||, fused epilogue.
// One wave per 16-row tile; W1 frags pre-arranged in LDS.
#define NT (N_NODES / 16)              // 6250 tiles
__global__ __launch_bounds__(256) void k_lin1(const float* __restrict__ x,
                                              const float* __restrict__ w1,
                                              const float* __restrict__ b1,
                                              float* __restrict__ xn,
                                              float* __restrict__ normv) {
    // B-fragment layout: frag f = (kt, lane): col=lane&15, k=kt*32+(lane>>4)*8
    __shared__ __align__(16) short bfH[16 * 64 * 8];   // 16 KB
    __shared__ __align__(16) short bfL[16 * 64 * 8];   // 16 KB

    const int t = threadIdx.x;
    for (int f = t; f < 16 * 64; f += 256) {
        const int kt  = f >> 6;
        const int ln  = f & 63;
        const int col = ln & 15;
        const int k0  = kt * 32 + (ln >> 4) * 8;
        const float4 v0 = *(const float4*)(w1 + col * N_FEAT + k0);
        const float4 v1 = *(const float4*)(w1 + col * N_FEAT + k0 + 4);
        bf16x8 hh, ll;
        short2 r;
        r = split_bf(v0.x); hh[0] = r.x; ll[0] = r.y;
        r = split_bf(v0.y); hh[1] = r.x; ll[1] = r.y;
        r = split_bf(v0.z); hh[2] = r.x; ll[2] = r.y;
        r = split_bf(v0.w); hh[3] = r.x; ll[3] = r.y;
        r = split_bf(v1.x); hh[4] = r.x; ll[4] = r.y;
        r = split_bf(v1.y); hh[5] = r.x; ll[5] = r.y;
        r = split_bf(v1.z); hh[6] = r.x; ll[6] = r.y;
        r = split_bf(v1.w); hh[7] = r.x; ll[7] = r.y;
        ((bf16x8*)bfH)[f] = hh;
        ((bf16x8*)bfL)[f] = ll;
    }
    __syncthreads();

    const int wv   = t >> 6;
    const int l    = t & 63;
    const int tile = blockIdx.x * 4 + wv;
    if (tile >= NT) return;

    const int r0 = tile * 16;
    const float* xp = x + (size_t)(r0 + (l & 15)) * N_FEAT + ((l >> 4) * 8);

    f32x4 acc = {0.f, 0.f, 0.f, 0.f};
    float4 c0 = *(const float4*)(xp);
    float4 c1 = *(const float4*)(xp + 4);
#pragma unroll
    for (int kt = 0; kt < 16; ++kt) {
        float4 n0, n1;
        if (kt < 15) {
            n0 = *(const float4*)(xp + (kt + 1) * 32);
            n1 = *(const float4*)(xp + (kt + 1) * 32 + 4);
        }
        bf16x8 ah, al;
        short2 r;
        r = split_bf(c0.x); ah[0] = r.x; al[0] = r.y;
        r = split_bf(c0.y); ah[1] = r.x; al[1] = r.y;
        r = split_bf(c0.z); ah[2] = r.x; al[2] = r.y;
        r = split_bf(c0.w); ah[3] = r.x; al[3] = r.y;
        r = split_bf(c1.x); ah[4] = r.x; al[4] = r.y;
        r = split_bf(c1.y); ah[5] = r.x; al[5] = r.y;
        r = split_bf(c1.z); ah[6] = r.x; al[6] = r.y;
        r = split_bf(c1.w); ah[7] = r.x; al[7] = r.y;
        const bf16x8 bh = ((const bf16x8*)bfH)[kt * 64 + l];
        const bf16x8 bl = ((const bf16x8*)bfL)[kt * 64 + l];
        acc = __builtin_amdgcn_mfma_f32_16x16x32_bf16(ah, bh, acc, 0, 0, 0);
        acc = __builtin_amdgcn_mfma_f32_16x16x32_bf16(al, bh, acc, 0, 0, 0);
        acc = __builtin_amdgcn_mfma_f32_16x16x32_bf16(ah, bl, acc, 0, 0, 0);
        c0 = n0; c1 = n1;
    }

    // C/D: col = lane&15, row = (lane>>4)*4 + reg. Fused relu + row-normalize:
    // the 16 lanes sharing (l>>4) hold the 16 cols of each row -> shfl reduce.
    const float bias = b1[l & 15];
#pragma unroll
    for (int r = 0; r < 4; ++r) {
        const float v = fmaxf(acc[r] + bias, 0.f);
        float ss = v * v;
        ss += __shfl_xor(ss, 1); ss += __shfl_xor(ss, 2);
        ss += __shfl_xor(ss, 4); ss += __shfl_xor(ss, 8);
        const float nrm = sqrtf(ss);
        const float rn  = 1.f / fmaxf(nrm, 1e-12f);
        const int row = r0 + (l >> 4) * 4 + r;
        xn[(size_t)row * HID + (l & 15)] = v * rn;
        if ((l & 15) == 0) normv[row] = nrm;
    }
}

// ============================== CSR build (binned) ==========================
__global__ __launch_bounds__(256) void k_zero(int* __restrict__ p, int n) {
    const int i = blockIdx.x * 256 + threadIdx.x;
    if (i < n) p[i] = 0;
}

// per-block LDS histogram of dst-buckets -> few global atomics
__global__ __launch_bounds__(256) void k_bhist(const int* __restrict__ dst,
                                               int* __restrict__ gcount) {
    __shared__ int h[NB];
    const int t = threadIdx.x;
    for (int i = t; i < NB; i += 256) h[i] = 0;
    __syncthreads();
    const int e0 = blockIdx.x * EPB;
#pragma unroll
    for (int k = 0; k < EPB / 256; k++) {
        const int e = e0 + k * 256 + t;
        if (e < N_EDGES) atomicAdd(&h[dst[e] >> BSHIFT], 1);
    }
    __syncthreads();
    for (int i = t; i < NB; i += 256)
        if (h[i]) atomicAdd(&gcount[i], h[i]);
}

// exclusive scan of 196 bucket counts -> bstart[NB+1] and write cursors
__global__ __launch_bounds__(256) void k_bscan(const int* __restrict__ gcount,
                                               int* __restrict__ bstart,
                                               int* __restrict__ cursor) {
    __shared__ int buf[256];
    const int t = threadIdx.x;
    const int v = (t < NB) ? gcount[t] : 0;
    buf[t] = v; __syncthreads();
    for (int o = 1; o < 256; o <<= 1) {
        const int a = (t >= o) ? buf[t - o] : 0;
        __syncthreads();
        buf[t] += a;
        __syncthreads();
    }
    if (t < NB) { const int ex = buf[t] - v; bstart[t] = ex; cursor[t] = ex; }
    if (t == 0) bstart[NB] = N_EDGES;
}

// group EPB edges by bucket in LDS, reserve contiguous chunks, flush coalesced.
// binned[] entry = (src << 9) | (dst & 511), grouped by bucket.
__global__ __launch_bounds__(256) void k_bin(const int* __restrict__ src,
                                             const int* __restrict__ dst,
                                             int* __restrict__ cursor,
                                             int* __restrict__ binned) {
    __shared__ int hist[NB];
    __shared__ int lofs[NB];
    __shared__ int base[NB];
    __shared__ int rk[NB];
    __shared__ int buf[256];
    __shared__ int stage[EPB];
    __shared__ unsigned short sbkt[EPB];

    const int t = threadIdx.x;
    for (int i = t; i < NB; i += 256) { hist[i] = 0; rk[i] = 0; }
    __syncthreads();

    const int e0 = blockIdx.x * EPB;
    int bk[EPB / 256];
    int vv[EPB / 256];
#pragma unroll
    for (int k = 0; k < EPB / 256; k++) {
        const int e = e0 + k * 256 + t;
        if (e < N_EDGES) {
            const int d = dst[e], s = src[e];
            bk[k] = d >> BSHIFT;
            vv[k] = (s << BSHIFT) | (d & BMASK);
            atomicAdd(&hist[bk[k]], 1);
        } else bk[k] = -1;
    }
    __syncthreads();

    // exclusive scan hist -> lofs
    {
        const int v = (t < NB) ? hist[t] : 0;
        buf[t] = v; __syncthreads();
        for (int o = 1; o < 256; o <<= 1) {
            const int a = (t >= o) ? buf[t - o] : 0;
            __syncthreads();
            buf[t] += a;
            __syncthreads();
        }
        if (t < NB) lofs[t] = buf[t] - v;
    }
    // reserve global chunk per bucket
    if (t < NB && hist[t] > 0) base[t] = atomicAdd(&cursor[t], hist[t]);

    // local scatter into stage (grouped by bucket)
#pragma unroll
    for (int k = 0; k < EPB / 256; k++) {
        if (bk[k] >= 0) {
            const int r = atomicAdd(&rk[bk[k]], 1);
            const int slot = lofs[bk[k]] + r;
            stage[slot] = vv[k];
            sbkt[slot] = (unsigned short)bk[k];
        }
    }
    __syncthreads();

    // flush: consecutive slots of a bucket -> consecutive global addresses
    const int nloc = min(EPB, N_EDGES - e0);
    for (int s2 = t; s2 < nloc; s2 += 256) {
        const int b = sbkt[s2];
        binned[base[b] + (s2 - lofs[b])] = stage[s2];
    }
}

// per bucket: counts per node, scan -> row_start, scatter srcs in LDS,
// write csr coalesced IN-PLACE over binned (per-block range, reads precede writes)
__global__ __launch_bounds__(512) void k_csr(const int* __restrict__ bstart,
                                             int* __restrict__ binned,
                                             int* __restrict__ row_start) {
    __shared__ int cnts[512];
    __shared__ int cur[512];
    __shared__ int buf[512];
    __shared__ int lcsr[CAP];

    const int t = threadIdx.x;
    const int b = blockIdx.x;
    const int s0 = bstart[b], s1 = bstart[b + 1];
    const int n = s1 - s0;

    cnts[t] = 0;
    __syncthreads();
    for (int i = t; i < n; i += 512)
        atomicAdd(&cnts[binned[s0 + i] & BMASK], 1);
    __syncthreads();

    // exclusive scan over 512
    {
        const int v = cnts[t];
        buf[t] = v; __syncthreads();
        for (int o = 1; o < 512; o <<= 1) {
            const int a = (t >= o) ? buf[t - o] : 0;
            __syncthreads();
            buf[t] += a;
            __syncthreads();
        }
        cur[t] = buf[t] - v;   // exclusive prefix
        const int node = (b << BSHIFT) + t;
        if (node < N_NODES) row_start[node] = s0 + cur[t];
        if (b == NB - 1 && t == 0) row_start[N_NODES] = N_EDGES;
    }
    __syncthreads();

    for (int i = t; i < n; i += 512) {
        const int v = binned[s0 + i];
        const int p = atomicAdd(&cur[v & BMASK], 1);
        lcsr[p] = v >> BSHIFT;
    }
    __syncthreads();

    for (int i = t; i < n; i += 512) binned[s0 + i] = lcsr[i];
}

// ============================== Fused AGNN gather ===========================
// 16 lanes per dst node; lane l owns feature l. Per 16-edge batch, lane g
// loads ONE xn[src_g] row (64 B), computes the cosine logit + weight, scales
// the row by w*norm[src_g] in registers, then a fused shfl_xor transpose-
// reduce (15 shuffles) deposits Sum_g w_g*h[src_g][l] on lane l. The h array
// is never materialized (h = xn*norm). EMIT_NORMED: epilogue also emits the
// next layer's unit rows + norms (replaces k_norm).
template <int EMIT_NORMED>
__global__ __launch_bounds__(256) void k_agnn(const int* __restrict__ row_start,
                                              const int* __restrict__ csr_src,
                                              const float* __restrict__ xn,
                                              const float* __restrict__ normv,
                                              const float* __restrict__ betap,
                                              float* __restrict__ out,
                                              float* __restrict__ out_norm) {
    const int l16  = threadIdx.x & 15;
    const int node = (blockIdx.x * 256 + threadIdx.x) >> 4;   // grid exact
    const float beta  = betap ? betap[0] : 1.0f;
    const float shift = fabsf(beta);

    const int rs = row_start[node];
    const int re = row_start[node + 1];

    const float4* xd = (const float4*)(xn + (size_t)node * HID);
    const float4 d0 = xd[0], d1 = xd[1], d2 = xd[2], d3 = xd[3];

    float acc = 0.f, sw = 0.f;
    for (int t = rs; t < re; t += 16) {
        const int k = t + l16;
        const bool ok = (k < re);
        const int sidx = ok ? csr_src[k] : 0;
        const float4* xs = (const float4*)(xn + (size_t)sidx * HID);
        const float4 a0 = xs[0], a1 = xs[1], a2 = xs[2], a3 = xs[3];
        const float dot =
              a0.x*d0.x + a0.y*d0.y + a0.z*d0.z + a0.w*d0.w
            + a1.x*d1.x + a1.y*d1.y + a1.z*d1.z + a1.w*d1.w
            + a2.x*d2.x + a2.y*d2.y + a2.z*d2.z + a2.w*d2.w
            + a3.x*d3.x + a3.y*d3.y + a3.z*d3.z + a3.w*d3.w;
        const float w = ok ? __expf(beta * dot - shift) : 0.f;

        // group-wide weight sum (all 16 lanes get the same value)
        float wsum = w;
        wsum += __shfl_xor(wsum, 1); wsum += __shfl_xor(wsum, 2);
        wsum += __shfl_xor(wsum, 4); wsum += __shfl_xor(wsum, 8);
        sw += wsum;

        // scale own row by w * ||h_src||
        const float s = w * normv[sidx];
        float d[16];
        d[0]=s*a0.x; d[1]=s*a0.y; d[2]=s*a0.z;  d[3]=s*a0.w;
        d[4]=s*a1.x; d[5]=s*a1.y; d[6]=s*a1.z;  d[7]=s*a1.w;
        d[8]=s*a2.x; d[9]=s*a2.y; d[10]=s*a2.z; d[11]=s*a2.w;
        d[12]=s*a3.x; d[13]=s*a3.y; d[14]=s*a3.z; d[15]=s*a3.w;

        // fused transpose-reduce: d[0] ends as Sum_g d_g[l16]
#pragma unroll
        for (int m = 1; m < 16; m <<= 1) {
#pragma unroll
            for (int r = 0; r < 16; r += 2 * m) {
                const float sel  = (l16 & m) ? d[r] : d[r + m];
                const float got  = __shfl_xor(sel, m);
                const float mine = (l16 & m) ? d[r + m] : d[r];
                d[r] = mine + got;
            }
        }
        acc += d[0];
    }

    const float v = acc / fmaxf(sw, 1e-16f);
    if (EMIT_NORMED) {
        float ss = v * v;
        ss += __shfl_xor(ss, 1); ss += __shfl_xor(ss, 2);
        ss += __shfl_xor(ss, 4); ss += __shfl_xor(ss, 8);
        const float nrm = sqrtf(ss);
        const float rn  = 1.f / fmaxf(nrm, 1e-12f);
        out[(size_t)node * HID + l16] = v * rn;
        if (l16 == 0) out_norm[node] = nrm;
    } else {
        out[(size_t)node * HID + l16] = v;
    }
}

// ============================== Stage 3 =====================================
__global__ __launch_bounds__(256) void k_lin2(const float* __restrict__ h,
                                              const float* __restrict__ w2,
                                              const float* __restrict__ b2,
                                              float* __restrict__ out) {
    __shared__ float w2s[N_CLASS][HID];
    __shared__ float b2s[N_CLASS];
    for (int i = threadIdx.x; i < N_CLASS * HID; i += 256)
        ((float*)w2s)[i] = w2[i];
    if (threadIdx.x < N_CLASS) b2s[threadIdx.x] = b2[threadIdx.x];
    __syncthreads();

    const int n = blockIdx.x * 256 + threadIdx.x;
    if (n >= N_NODES) return;

    float hv[HID];
    const float4* hr = (const float4*)(h + (size_t)n * HID);
#pragma unroll
    for (int q = 0; q < 4; q++) {
        const float4 v = hr[q];
        hv[q*4+0]=v.x; hv[q*4+1]=v.y; hv[q*4+2]=v.z; hv[q*4+3]=v.w;
    }

    float lg[N_CLASS];
    float m = -3.0e38f;
#pragma unroll
    for (int j = 0; j < N_CLASS; j++) {
        float acc = b2s[j];
#pragma unroll
        for (int k = 0; k < HID; k++) acc += hv[k] * w2s[j][k];
        lg[j] = acc;
        m = fmaxf(m, acc);
    }
    float sum = 0.f;
#pragma unroll
    for (int j = 0; j < N_CLASS; j++) sum += __expf(lg[j] - m);
    const float lse = m + __logf(sum);

    float4* orow = (float4*)(out + (size_t)n * N_CLASS);
#pragma unroll
    for (int q = 0; q < N_CLASS / 4; q++) {
        float4 o;
        o.x = lg[q*4+0] - lse;
        o.y = lg[q*4+1] - lse;
        o.z = lg[q*4+2] - lse;
        o.w = lg[q*4+3] - lse;
        orow[q] = o;
    }
}

// ============================== Launch ======================================
extern "C" void kernel_launch(void* const* d_in, const int* in_sizes, int n_in,
                              void* d_out, int out_size, void* d_ws, size_t ws_size,
                              hipStream_t stream) {
    const float* x     = (const float*)d_in[0];
    const int*   ei    = (const int*)  d_in[1];   // [2][E]: row0=src, row1=dst
    const float* w1    = (const float*)d_in[2];
    const float* b1    = (const float*)d_in[3];
    const float* beta2 = (const float*)d_in[4];
    const float* w2    = (const float*)d_in[5];
    const float* b2    = (const float*)d_in[6];
    float* out = (float*)d_out;

    const int* srcp = ei;
    const int* dstp = ei + N_EDGES;

    // workspace layout
    float* xn1   = (float*)d_ws;                       // [N,16] unit rows
    float* norm1 = xn1 + (size_t)N_NODES * HID;        // [N]
    float* xn2   = norm1 + N_NODES;                    // [N,16]
    float* norm2 = xn2 + (size_t)N_NODES * HID;        // [N]
    float* hF    = norm2 + N_NODES;                    // [N,16] final features
    int* row_start = (int*)(hF + (size_t)N_NODES * HID); // [N+1]
    int* gcount    = row_start + N_NODES + 1;          // [NB]
    int* bstart    = gcount + NB;                      // [NB+1]
    int* cursor    = bstart + NB + 1;                  // [NB]
    int* binned    = cursor + NB;                      // [E] packed, then csr_src

    const int nodeGrid = (N_NODES + 255) / 256;        // 391
    const int lin1Grid = (NT + 3) / 4;                 // 1563 (4 waves/block)
    const int binGrid  = (N_EDGES + EPB - 1) / EPB;    // 782
    const int agnnGrid = N_NODES * HID / 256;          // 6250

    // ---- CSR build: coalesced two-level binning ----
    k_zero <<<1,       256, 0, stream>>>(gcount, NB);
    k_bhist<<<binGrid, 256, 0, stream>>>(dstp, gcount);
    k_bscan<<<1,       256, 0, stream>>>(gcount, bstart, cursor);
    k_bin  <<<binGrid, 256, 0, stream>>>(srcp, dstp, cursor, binned);
    k_csr  <<<NB,      512, 0, stream>>>(bstart, binned, row_start);

    // ---- network (norms fused into producers) ----
    k_lin1<<<lin1Grid, 256, 0, stream>>>(x, w1, b1, xn1, norm1);

    k_agnn<1><<<agnnGrid, 256, 0, stream>>>(row_start, binned, xn1, norm1,
                                            nullptr, xn2, norm2);
    k_agnn<0><<<agnnGrid, 256, 0, stream>>>(row_start, binned, xn2, norm2,
                                            beta2, hF, nullptr);

    k_lin2<<<nodeGrid, 256, 0, stream>>>(hF, w2, b2, out);
}

// Round 7
// 275.600 us; speedup vs baseline: 1.3891x; 1.3891x over previous
//
#include <hip/hip_runtime.h>

#define N_NODES 100000
#define N_EDGES 3200000
#define N_FEAT  512
#define HID     16
#define N_CLASS 40

#define BSHIFT  9                      // 512 nodes per bucket
#define BMASK   ((1 << BSHIFT) - 1)
#define NB      196                    // ceil(100000 / 512)
#define CAP     18432                  // max edges/bucket (mean 16384, +16 sigma)
#define EPB     4096                   // edges per binning block

typedef __attribute__((ext_vector_type(8))) short bf16x8;
typedef __attribute__((ext_vector_type(4))) float f32x4;

// exact split: v == hi_f32 + lo_residual; hi = truncated-top-16 (exact),
// lo = bf16(v - hi) (residual <= 2^-8 |v|, its bf16 trunc err <= 2^-16 |v|)
__device__ inline short2 split_bf(float v) {
    const unsigned u = __float_as_uint(v);
    const short hi = (short)(u >> 16);
    const float hf = __uint_as_float(u & 0xFFFF0000u);
    const short lo = (short)(__float_as_uint(v - hf) >> 16);
    return make_short2(hi, lo);
}

// ============================== Stage 1 (MFMA) ==============================
// xn = rownorm(relu(x @ W1^T + b1)), norm = ||row||, fused epilogue.
// One wave per 16-row tile; W1 frags pre-arranged in LDS.
#define NT (N_NODES / 16)              // 6250 tiles
__global__ __launch_bounds__(256) void k_lin1(const float* __restrict__ x,
                                              const float* __restrict__ w1,
                                              const float* __restrict__ b1,
                                              float* __restrict__ xn,
                                              float* __restrict__ normv) {
    // B-fragment layout: frag f = (kt, lane): col=lane&15, k=kt*32+(lane>>4)*8
    __shared__ __align__(16) short bfH[16 * 64 * 8];   // 16 KB
    __shared__ __align__(16) short bfL[16 * 64 * 8];   // 16 KB

    const int t = threadIdx.x;
    for (int f = t; f < 16 * 64; f += 256) {
        const int kt  = f >> 6;
        const int ln  = f & 63;
        const int col = ln & 15;
        const int k0  = kt * 32 + (ln >> 4) * 8;
        const float4 v0 = *(const float4*)(w1 + col * N_FEAT + k0);
        const float4 v1 = *(const float4*)(w1 + col * N_FEAT + k0 + 4);
        bf16x8 hh, ll;
        short2 r;
        r = split_bf(v0.x); hh[0] = r.x; ll[0] = r.y;
        r = split_bf(v0.y); hh[1] = r.x; ll[1] = r.y;
        r = split_bf(v0.z); hh[2] = r.x; ll[2] = r.y;
        r = split_bf(v0.w); hh[3] = r.x; ll[3] = r.y;
        r = split_bf(v1.x); hh[4] = r.x; ll[4] = r.y;
        r = split_bf(v1.y); hh[5] = r.x; ll[5] = r.y;
        r = split_bf(v1.z); hh[6] = r.x; ll[6] = r.y;
        r = split_bf(v1.w); hh[7] = r.x; ll[7] = r.y;
        ((bf16x8*)bfH)[f] = hh;
        ((bf16x8*)bfL)[f] = ll;
    }
    __syncthreads();

    const int wv   = t >> 6;
    const int l    = t & 63;
    const int tile = blockIdx.x * 4 + wv;
    if (tile >= NT) return;

    const int r0 = tile * 16;
    const float* xp = x + (size_t)(r0 + (l & 15)) * N_FEAT + ((l >> 4) * 8);

    f32x4 acc = {0.f, 0.f, 0.f, 0.f};
    float4 c0 = *(const float4*)(xp);
    float4 c1 = *(const float4*)(xp + 4);
#pragma unroll
    for (int kt = 0; kt < 16; ++kt) {
        float4 n0, n1;
        if (kt < 15) {
            n0 = *(const float4*)(xp + (kt + 1) * 32);
            n1 = *(const float4*)(xp + (kt + 1) * 32 + 4);
        }
        bf16x8 ah, al;
        short2 r;
        r = split_bf(c0.x); ah[0] = r.x; al[0] = r.y;
        r = split_bf(c0.y); ah[1] = r.x; al[1] = r.y;
        r = split_bf(c0.z); ah[2] = r.x; al[2] = r.y;
        r = split_bf(c0.w); ah[3] = r.x; al[3] = r.y;
        r = split_bf(c1.x); ah[4] = r.x; al[4] = r.y;
        r = split_bf(c1.y); ah[5] = r.x; al[5] = r.y;
        r = split_bf(c1.z); ah[6] = r.x; al[6] = r.y;
        r = split_bf(c1.w); ah[7] = r.x; al[7] = r.y;
        const bf16x8 bh = ((const bf16x8*)bfH)[kt * 64 + l];
        const bf16x8 bl = ((const bf16x8*)bfL)[kt * 64 + l];
        acc = __builtin_amdgcn_mfma_f32_16x16x32_bf16(ah, bh, acc, 0, 0, 0);
        acc = __builtin_amdgcn_mfma_f32_16x16x32_bf16(al, bh, acc, 0, 0, 0);
        acc = __builtin_amdgcn_mfma_f32_16x16x32_bf16(ah, bl, acc, 0, 0, 0);
        c0 = n0; c1 = n1;
    }

    // C/D: col = lane&15, row = (lane>>4)*4 + reg. Fused relu + row-normalize:
    // the 16 lanes sharing (l>>4) hold the 16 cols of each row -> shfl reduce.
    const float bias = b1[l & 15];
#pragma unroll
    for (int r = 0; r < 4; ++r) {
        const float v = fmaxf(acc[r] + bias, 0.f);
        float ss = v * v;
        ss += __shfl_xor(ss, 1); ss += __shfl_xor(ss, 2);
        ss += __shfl_xor(ss, 4); ss += __shfl_xor(ss, 8);
        const float nrm = sqrtf(ss);
        const float rn  = 1.f / fmaxf(nrm, 1e-12f);
        const int row = r0 + (l >> 4) * 4 + r;
        xn[(size_t)row * HID + (l & 15)] = v * rn;
        if ((l & 15) == 0) normv[row] = nrm;
    }
}

// ============================== CSR build (binned) ==========================
__global__ __launch_bounds__(256) void k_zero(int* __restrict__ p, int n) {
    const int i = blockIdx.x * 256 + threadIdx.x;
    if (i < n) p[i] = 0;
}

// per-block LDS histogram of dst-buckets -> few global atomics
__global__ __launch_bounds__(256) void k_bhist(const int* __restrict__ dst,
                                               int* __restrict__ gcount) {
    __shared__ int h[NB];
    const int t = threadIdx.x;
    for (int i = t; i < NB; i += 256) h[i] = 0;
    __syncthreads();
    const int e0 = blockIdx.x * EPB;
#pragma unroll
    for (int k = 0; k < EPB / 256; k++) {
        const int e = e0 + k * 256 + t;
        if (e < N_EDGES) atomicAdd(&h[dst[e] >> BSHIFT], 1);
    }
    __syncthreads();
    for (int i = t; i < NB; i += 256)
        if (h[i]) atomicAdd(&gcount[i], h[i]);
}

// exclusive scan of 196 bucket counts -> bstart[NB+1] and write cursors
__global__ __launch_bounds__(256) void k_bscan(const int* __restrict__ gcount,
                                               int* __restrict__ bstart,
                                               int* __restrict__ cursor) {
    __shared__ int buf[256];
    const int t = threadIdx.x;
    const int v = (t < NB) ? gcount[t] : 0;
    buf[t] = v; __syncthreads();
    for (int o = 1; o < 256; o <<= 1) {
        const int a = (t >= o) ? buf[t - o] : 0;
        __syncthreads();
        buf[t] += a;
        __syncthreads();
    }
    if (t < NB) { const int ex = buf[t] - v; bstart[t] = ex; cursor[t] = ex; }
    if (t == 0) bstart[NB] = N_EDGES;
}

// group EPB edges by bucket in LDS, reserve contiguous chunks, flush coalesced.
// binned[] entry = (src << 9) | (dst & 511), grouped by bucket.
__global__ __launch_bounds__(256) void k_bin(const int* __restrict__ src,
                                             const int* __restrict__ dst,
                                             int* __restrict__ cursor,
                                             int* __restrict__ binned) {
    __shared__ int hist[NB];
    __shared__ int lofs[NB];
    __shared__ int base[NB];
    __shared__ int rk[NB];
    __shared__ int buf[256];
    __shared__ int stage[EPB];
    __shared__ unsigned short sbkt[EPB];

    const int t = threadIdx.x;
    for (int i = t; i < NB; i += 256) { hist[i] = 0; rk[i] = 0; }
    __syncthreads();

    const int e0 = blockIdx.x * EPB;
    int bk[EPB / 256];
    int vv[EPB / 256];
#pragma unroll
    for (int k = 0; k < EPB / 256; k++) {
        const int e = e0 + k * 256 + t;
        if (e < N_EDGES) {
            const int d = dst[e], s = src[e];
            bk[k] = d >> BSHIFT;
            vv[k] = (s << BSHIFT) | (d & BMASK);
            atomicAdd(&hist[bk[k]], 1);
        } else bk[k] = -1;
    }
    __syncthreads();

    // exclusive scan hist -> lofs
    {
        const int v = (t < NB) ? hist[t] : 0;
        buf[t] = v; __syncthreads();
        for (int o = 1; o < 256; o <<= 1) {
            const int a = (t >= o) ? buf[t - o] : 0;
            __syncthreads();
            buf[t] += a;
            __syncthreads();
        }
        if (t < NB) lofs[t] = buf[t] - v;
    }
    // reserve global chunk per bucket
    if (t < NB && hist[t] > 0) base[t] = atomicAdd(&cursor[t], hist[t]);

    // local scatter into stage (grouped by bucket)
#pragma unroll
    for (int k = 0; k < EPB / 256; k++) {
        if (bk[k] >= 0) {
            const int r = atomicAdd(&rk[bk[k]], 1);
            const int slot = lofs[bk[k]] + r;
            stage[slot] = vv[k];
            sbkt[slot] = (unsigned short)bk[k];
        }
    }
    __syncthreads();

    // flush: consecutive slots of a bucket -> consecutive global addresses
    const int nloc = min(EPB, N_EDGES - e0);
    for (int s2 = t; s2 < nloc; s2 += 256) {
        const int b = sbkt[s2];
        binned[base[b] + (s2 - lofs[b])] = stage[s2];
    }
}

// per bucket: counts per node, scan -> row_start, scatter srcs in LDS,
// write csr coalesced IN-PLACE over binned (per-block range, reads precede writes)
__global__ __launch_bounds__(512) void k_csr(const int* __restrict__ bstart,
                                             int* __restrict__ binned,
                                             int* __restrict__ row_start) {
    __shared__ int cnts[512];
    __shared__ int cur[512];
    __shared__ int buf[512];
    __shared__ int lcsr[CAP];

    const int t = threadIdx.x;
    const int b = blockIdx.x;
    const int s0 = bstart[b], s1 = bstart[b + 1];
    const int n = s1 - s0;

    cnts[t] = 0;
    __syncthreads();
    for (int i = t; i < n; i += 512)
        atomicAdd(&cnts[binned[s0 + i] & BMASK], 1);
    __syncthreads();

    // exclusive scan over 512
    {
        const int v = cnts[t];
        buf[t] = v; __syncthreads();
        for (int o = 1; o < 512; o <<= 1) {
            const int a = (t >= o) ? buf[t - o] : 0;
            __syncthreads();
            buf[t] += a;
            __syncthreads();
        }
        cur[t] = buf[t] - v;   // exclusive prefix
        const int node = (b << BSHIFT) + t;
        if (node < N_NODES) row_start[node] = s0 + cur[t];
        if (b == NB - 1 && t == 0) row_start[N_NODES] = N_EDGES;
    }
    __syncthreads();

    for (int i = t; i < n; i += 512) {
        const int v = binned[s0 + i];
        const int p = atomicAdd(&cur[v & BMASK], 1);
        lcsr[p] = v >> BSHIFT;
    }
    __syncthreads();

    for (int i = t; i < n; i += 512) binned[s0 + i] = lcsr[i];
}

// ============================== Fused AGNN gather ===========================
// 16 lanes per dst node; lane l owns feature l. Lane g computes edge g's
// cosine logit; (w*norm[src], src) broadcast via __shfl; lane l accumulates
// its feature via L1-hot scalar re-loads of xn (the row was just fetched by
// lane g of the group -> same 64 B line). h is never materialized (h=xn*norm).
// Two accumulators break the serial FMA chain. No atomics.
template <int EMIT_NORMED>
__global__ __launch_bounds__(256) void k_agnn(const int* __restrict__ row_start,
                                              const int* __restrict__ csr_src,
                                              const float* __restrict__ xn,
                                              const float* __restrict__ normv,
                                              const float* __restrict__ betap,
                                              float* __restrict__ out,
                                              float* __restrict__ out_norm) {
    const int l16  = threadIdx.x & 15;
    const int node = (blockIdx.x * 256 + threadIdx.x) >> 4;   // grid exact
    const float beta  = betap ? betap[0] : 1.0f;
    const float shift = fabsf(beta);

    const int rs = row_start[node];
    const int re = row_start[node + 1];

    const float4* xd = (const float4*)(xn + (size_t)node * HID);
    const float4 d0 = xd[0], d1 = xd[1], d2 = xd[2], d3 = xd[3];

    const float* colp = xn + l16;        // lane's feature column base
    float acc0 = 0.f, acc1 = 0.f, sw = 0.f;

    for (int t = rs; t < re; t += 16) {
        const int k = t + l16;
        const bool ok = (k < re);
        const int sidx = ok ? csr_src[k] : 0;
        const float4* xs = (const float4*)(xn + (size_t)sidx * HID);
        const float4 a0 = xs[0], a1 = xs[1], a2 = xs[2], a3 = xs[3];
        const float nj = normv[sidx];
        const float dot =
              a0.x*d0.x + a0.y*d0.y + a0.z*d0.z + a0.w*d0.w
            + a1.x*d1.x + a1.y*d1.y + a1.z*d1.z + a1.w*d1.w
            + a2.x*d2.x + a2.y*d2.y + a2.z*d2.z + a2.w*d2.w
            + a3.x*d3.x + a3.y*d3.y + a3.z*d3.z + a3.w*d3.w;
        const float w = ok ? __expf(beta * dot - shift) : 0.f;

        // group weight sum (4 independent-ish shuffles)
        float ws = w;
        ws += __shfl_xor(ws, 1); ws += __shfl_xor(ws, 2);
        ws += __shfl_xor(ws, 4); ws += __shfl_xor(ws, 8);
        sw += ws;

        const float wn = w * nj;         // fold ||h_src|| into the weight
#pragma unroll
        for (int j = 0; j < 16; j += 2) {
            const float w0 = __shfl(wn, j, 16);
            const int   s0i = __shfl(sidx, j, 16);
            const float w1 = __shfl(wn, j + 1, 16);
            const int   s1i = __shfl(sidx, j + 1, 16);
            acc0 += w0 * colp[(size_t)s0i * HID];
            acc1 += w1 * colp[(size_t)s1i * HID];
        }
    }

    const float v = (acc0 + acc1) / fmaxf(sw, 1e-16f);
    if (EMIT_NORMED) {
        float ss = v * v;
        ss += __shfl_xor(ss, 1); ss += __shfl_xor(ss, 2);
        ss += __shfl_xor(ss, 4); ss += __shfl_xor(ss, 8);
        const float nrm = sqrtf(ss);
        const float rn  = 1.f / fmaxf(nrm, 1e-12f);
        out[(size_t)node * HID + l16] = v * rn;
        if (l16 == 0) out_norm[node] = nrm;
    } else {
        out[(size_t)node * HID + l16] = v;
    }
}

// ============================== Stage 3 =====================================
__global__ __launch_bounds__(256) void k_lin2(const float* __restrict__ h,
                                              const float* __restrict__ w2,
                                              const float* __restrict__ b2,
                                              float* __restrict__ out) {
    __shared__ float w2s[N_CLASS][HID];
    __shared__ float b2s[N_CLASS];
    for (int i = threadIdx.x; i < N_CLASS * HID; i += 256)
        ((float*)w2s)[i] = w2[i];
    if (threadIdx.x < N_CLASS) b2s[threadIdx.x] = b2[threadIdx.x];
    __syncthreads();

    const int n = blockIdx.x * 256 + threadIdx.x;
    if (n >= N_NODES) return;

    float hv[HID];
    const float4* hr = (const float4*)(h + (size_t)n * HID);
#pragma unroll
    for (int q = 0; q < 4; q++) {
        const float4 v = hr[q];
        hv[q*4+0]=v.x; hv[q*4+1]=v.y; hv[q*4+2]=v.z; hv[q*4+3]=v.w;
    }

    float lg[N_CLASS];
    float m = -3.0e38f;
#pragma unroll
    for (int j = 0; j < N_CLASS; j++) {
        float acc = b2s[j];
#pragma unroll
        for (int k = 0; k < HID; k++) acc += hv[k] * w2s[j][k];
        lg[j] = acc;
        m = fmaxf(m, acc);
    }
    float sum = 0.f;
#pragma unroll
    for (int j = 0; j < N_CLASS; j++) sum += __expf(lg[j] - m);
    const float lse = m + __logf(sum);

    float4* orow = (float4*)(out + (size_t)n * N_CLASS);
#pragma unroll
    for (int q = 0; q < N_CLASS / 4; q++) {
        float4 o;
        o.x = lg[q*4+0] - lse;
        o.y = lg[q*4+1] - lse;
        o.z = lg[q*4+2] - lse;
        o.w = lg[q*4+3] - lse;
        orow[q] = o;
    }
}

// ============================== Launch ======================================
extern "C" void kernel_launch(void* const* d_in, const int* in_sizes, int n_in,
                              void* d_out, int out_size, void* d_ws, size_t ws_size,
                              hipStream_t stream) {
    const float* x     = (const float*)d_in[0];
    const int*   ei    = (const int*)  d_in[1];   // [2][E]: row0=src, row1=dst
    const float* w1    = (const float*)d_in[2];
    const float* b1    = (const float*)d_in[3];
    const float* beta2 = (const float*)d_in[4];
    const float* w2    = (const float*)d_in[5];
    const float* b2    = (const float*)d_in[6];
    float* out = (float*)d_out;

    const int* srcp = ei;
    const int* dstp = ei + N_EDGES;

    // workspace layout
    float* xn1   = (float*)d_ws;                       // [N,16] unit rows
    float* norm1 = xn1 + (size_t)N_NODES * HID;        // [N]
    float* xn2   = norm1 + N_NODES;                    // [N,16]
    float* norm2 = xn2 + (size_t)N_NODES * HID;        // [N]
    float* hF    = norm2 + N_NODES;                    // [N,16] final features
    int* row_start = (int*)(hF + (size_t)N_NODES * HID); // [N+1]
    int* gcount    = row_start + N_NODES + 1;          // [NB]
    int* bstart    = gcount + NB;                      // [NB+1]
    int* cursor    = bstart + NB + 1;                  // [NB]
    int* binned    = cursor + NB;                      // [E] packed, then csr_src

    const int nodeGrid = (N_NODES + 255) / 256;        // 391
    const int lin1Grid = (NT + 3) / 4;                 // 1563 (4 waves/block)
    const int binGrid  = (N_EDGES + EPB - 1) / EPB;    // 782
    const int agnnGrid = N_NODES * HID / 256;          // 6250

    // ---- CSR build: coalesced two-level binning ----
    k_zero <<<1,       256, 0, stream>>>(gcount, NB);
    k_bhist<<<binGrid, 256, 0, stream>>>(dstp, gcount);
    k_bscan<<<1,       256, 0, stream>>>(gcount, bstart, cursor);
    k_bin  <<<binGrid, 256, 0, stream>>>(srcp, dstp, cursor, binned);
    k_csr  <<<NB,      512, 0, stream>>>(bstart, binned, row_start);

    // ---- network (norms fused into producers) ----
    k_lin1<<<lin1Grid, 256, 0, stream>>>(x, w1, b1, xn1, norm1);

    k_agnn<1><<<agnnGrid, 256, 0, stream>>>(row_start, binned, xn1, norm1,
                                            nullptr, xn2, norm2);
    k_agnn<0><<<agnnGrid, 256, 0, stream>>>(row_start, binned, xn2, norm2,
                                            beta2, hF, nullptr);

    k_lin2<<<nodeGrid, 256, 0, stream>>>(hF, w2, b2, out);
}

// Round 8
// 255.757 us; speedup vs baseline: 1.4969x; 1.0776x over previous
//
#include <hip/hip_runtime.h>

#define N_NODES 100000
#define N_EDGES 3200000
#define N_FEAT  512
#define HID     16
#define N_CLASS 40

#define BSHIFT  9                      // 512 nodes per bucket
#define BMASK   ((1 << BSHIFT) - 1)
#define NB      196                    // ceil(100000 / 512)
#define CAP     18432                  // max edges/bucket (mean 16384, +16 sigma)
#define EPB     4096                   // edges per binning block

typedef __attribute__((ext_vector_type(8))) short bf16x8;
typedef __attribute__((ext_vector_type(4))) float f32x4;

// exact split: v == hi_f32 + lo_residual; hi = truncated-top-16 (exact),
// lo = bf16(v - hi) (residual <= 2^-8 |v|, its bf16 trunc err <= 2^-16 |v|)
__device__ inline short2 split_bf(float v) {
    const unsigned u = __float_as_uint(v);
    const short hi = (short)(u >> 16);
    const float hf = __uint_as_float(u & 0xFFFF0000u);
    const short lo = (short)(__float_as_uint(v - hf) >> 16);
    return make_short2(hi, lo);
}

// round-to-nearest-even bf16 (half the error of truncation)
__device__ inline unsigned short f2bf_rtn(float v) {
    unsigned u = __float_as_uint(v);
    u += 0x7FFFu + ((u >> 16) & 1u);
    return (unsigned short)(u >> 16);
}
__device__ inline float bf2f(unsigned short u) {
    return __uint_as_float(((unsigned)u) << 16);
}

// ============================== Stage 1 (MFMA) ==============================
// xnb = bf16(rownorm(relu(x @ W1^T + b1))), norm = ||row||, fused epilogue.
// One wave per 16-row tile; W1 frags pre-arranged in LDS.
#define NT (N_NODES / 16)              // 6250 tiles
__global__ __launch_bounds__(256) void k_lin1(const float* __restrict__ x,
                                              const float* __restrict__ w1,
                                              const float* __restrict__ b1,
                                              unsigned short* __restrict__ xnb,
                                              float* __restrict__ normv) {
    // B-fragment layout: frag f = (kt, lane): col=lane&15, k=kt*32+(lane>>4)*8
    __shared__ __align__(16) short bfH[16 * 64 * 8];   // 16 KB
    __shared__ __align__(16) short bfL[16 * 64 * 8];   // 16 KB

    const int t = threadIdx.x;
    for (int f = t; f < 16 * 64; f += 256) {
        const int kt  = f >> 6;
        const int ln  = f & 63;
        const int col = ln & 15;
        const int k0  = kt * 32 + (ln >> 4) * 8;
        const float4 v0 = *(const float4*)(w1 + col * N_FEAT + k0);
        const float4 v1 = *(const float4*)(w1 + col * N_FEAT + k0 + 4);
        bf16x8 hh, ll;
        short2 r;
        r = split_bf(v0.x); hh[0] = r.x; ll[0] = r.y;
        r = split_bf(v0.y); hh[1] = r.x; ll[1] = r.y;
        r = split_bf(v0.z); hh[2] = r.x; ll[2] = r.y;
        r = split_bf(v0.w); hh[3] = r.x; ll[3] = r.y;
        r = split_bf(v1.x); hh[4] = r.x; ll[4] = r.y;
        r = split_bf(v1.y); hh[5] = r.x; ll[5] = r.y;
        r = split_bf(v1.z); hh[6] = r.x; ll[6] = r.y;
        r = split_bf(v1.w); hh[7] = r.x; ll[7] = r.y;
        ((bf16x8*)bfH)[f] = hh;
        ((bf16x8*)bfL)[f] = ll;
    }
    __syncthreads();

    const int wv   = t >> 6;
    const int l    = t & 63;
    const int tile = blockIdx.x * 4 + wv;
    if (tile >= NT) return;

    const int r0 = tile * 16;
    const float* xp = x + (size_t)(r0 + (l & 15)) * N_FEAT + ((l >> 4) * 8);

    f32x4 acc = {0.f, 0.f, 0.f, 0.f};
    float4 c0 = *(const float4*)(xp);
    float4 c1 = *(const float4*)(xp + 4);
#pragma unroll
    for (int kt = 0; kt < 16; ++kt) {
        float4 n0, n1;
        if (kt < 15) {
            n0 = *(const float4*)(xp + (kt + 1) * 32);
            n1 = *(const float4*)(xp + (kt + 1) * 32 + 4);
        }
        bf16x8 ah, al;
        short2 r;
        r = split_bf(c0.x); ah[0] = r.x; al[0] = r.y;
        r = split_bf(c0.y); ah[1] = r.x; al[1] = r.y;
        r = split_bf(c0.z); ah[2] = r.x; al[2] = r.y;
        r = split_bf(c0.w); ah[3] = r.x; al[3] = r.y;
        r = split_bf(c1.x); ah[4] = r.x; al[4] = r.y;
        r = split_bf(c1.y); ah[5] = r.x; al[5] = r.y;
        r = split_bf(c1.z); ah[6] = r.x; al[6] = r.y;
        r = split_bf(c1.w); ah[7] = r.x; al[7] = r.y;
        const bf16x8 bh = ((const bf16x8*)bfH)[kt * 64 + l];
        const bf16x8 bl = ((const bf16x8*)bfL)[kt * 64 + l];
        acc = __builtin_amdgcn_mfma_f32_16x16x32_bf16(ah, bh, acc, 0, 0, 0);
        acc = __builtin_amdgcn_mfma_f32_16x16x32_bf16(al, bh, acc, 0, 0, 0);
        acc = __builtin_amdgcn_mfma_f32_16x16x32_bf16(ah, bl, acc, 0, 0, 0);
        c0 = n0; c1 = n1;
    }

    // C/D: col = lane&15, row = (lane>>4)*4 + reg. Fused relu + row-normalize.
    const float bias = b1[l & 15];
#pragma unroll
    for (int r = 0; r < 4; ++r) {
        const float v = fmaxf(acc[r] + bias, 0.f);
        float ss = v * v;
        ss += __shfl_xor(ss, 1); ss += __shfl_xor(ss, 2);
        ss += __shfl_xor(ss, 4); ss += __shfl_xor(ss, 8);
        const float nrm = sqrtf(ss);
        const float rn  = 1.f / fmaxf(nrm, 1e-12f);
        const int row = r0 + (l >> 4) * 4 + r;
        xnb[(size_t)row * HID + (l & 15)] = f2bf_rtn(v * rn);
        if ((l & 15) == 0) normv[row] = nrm;
    }
}

// ============================== CSR build (binned) ==========================
__global__ __launch_bounds__(256) void k_zero(int* __restrict__ p, int n) {
    const int i = blockIdx.x * 256 + threadIdx.x;
    if (i < n) p[i] = 0;
}

// per-block LDS histogram of dst-buckets -> few global atomics
__global__ __launch_bounds__(256) void k_bhist(const int* __restrict__ dst,
                                               int* __restrict__ gcount) {
    __shared__ int h[NB];
    const int t = threadIdx.x;
    for (int i = t; i < NB; i += 256) h[i] = 0;
    __syncthreads();
    const int e0 = blockIdx.x * EPB;
#pragma unroll
    for (int k = 0; k < EPB / 256; k++) {
        const int e = e0 + k * 256 + t;
        if (e < N_EDGES) atomicAdd(&h[dst[e] >> BSHIFT], 1);
    }
    __syncthreads();
    for (int i = t; i < NB; i += 256)
        if (h[i]) atomicAdd(&gcount[i], h[i]);
}

// exclusive scan of 196 bucket counts -> bstart[NB+1] and write cursors
__global__ __launch_bounds__(256) void k_bscan(const int* __restrict__ gcount,
                                               int* __restrict__ bstart,
                                               int* __restrict__ cursor) {
    __shared__ int buf[256];
    const int t = threadIdx.x;
    const int v = (t < NB) ? gcount[t] : 0;
    buf[t] = v; __syncthreads();
    for (int o = 1; o < 256; o <<= 1) {
        const int a = (t >= o) ? buf[t - o] : 0;
        __syncthreads();
        buf[t] += a;
        __syncthreads();
    }
    if (t < NB) { const int ex = buf[t] - v; bstart[t] = ex; cursor[t] = ex; }
    if (t == 0) bstart[NB] = N_EDGES;
}

// group EPB edges by bucket in LDS, reserve contiguous chunks, flush coalesced.
// binned[] entry = (src << 9) | (dst & 511), grouped by bucket.
__global__ __launch_bounds__(256) void k_bin(const int* __restrict__ src,
                                             const int* __restrict__ dst,
                                             int* __restrict__ cursor,
                                             int* __restrict__ binned) {
    __shared__ int hist[NB];
    __shared__ int lofs[NB];
    __shared__ int base[NB];
    __shared__ int rk[NB];
    __shared__ int buf[256];
    __shared__ int stage[EPB];
    __shared__ unsigned short sbkt[EPB];

    const int t = threadIdx.x;
    for (int i = t; i < NB; i += 256) { hist[i] = 0; rk[i] = 0; }
    __syncthreads();

    const int e0 = blockIdx.x * EPB;
    int bk[EPB / 256];
    int vv[EPB / 256];
#pragma unroll
    for (int k = 0; k < EPB / 256; k++) {
        const int e = e0 + k * 256 + t;
        if (e < N_EDGES) {
            const int d = dst[e], s = src[e];
            bk[k] = d >> BSHIFT;
            vv[k] = (s << BSHIFT) | (d & BMASK);
            atomicAdd(&hist[bk[k]], 1);
        } else bk[k] = -1;
    }
    __syncthreads();

    // exclusive scan hist -> lofs
    {
        const int v = (t < NB) ? hist[t] : 0;
        buf[t] = v; __syncthreads();
        for (int o = 1; o < 256; o <<= 1) {
            const int a = (t >= o) ? buf[t - o] : 0;
            __syncthreads();
            buf[t] += a;
            __syncthreads();
        }
        if (t < NB) lofs[t] = buf[t] - v;
    }
    // reserve global chunk per bucket
    if (t < NB && hist[t] > 0) base[t] = atomicAdd(&cursor[t], hist[t]);

    // local scatter into stage (grouped by bucket)
#pragma unroll
    for (int k = 0; k < EPB / 256; k++) {
        if (bk[k] >= 0) {
            const int r = atomicAdd(&rk[bk[k]], 1);
            const int slot = lofs[bk[k]] + r;
            stage[slot] = vv[k];
            sbkt[slot] = (unsigned short)bk[k];
        }
    }
    __syncthreads();

    // flush: consecutive slots of a bucket -> consecutive global addresses
    const int nloc = min(EPB, N_EDGES - e0);
    for (int s2 = t; s2 < nloc; s2 += 256) {
        const int b = sbkt[s2];
        binned[base[b] + (s2 - lofs[b])] = stage[s2];
    }
}

// per bucket: counts per node, scan -> row_start, scatter srcs in LDS,
// write csr coalesced IN-PLACE over binned (per-block range, reads precede writes)
__global__ __launch_bounds__(512) void k_csr(const int* __restrict__ bstart,
                                             int* __restrict__ binned,
                                             int* __restrict__ row_start) {
    __shared__ int cnts[512];
    __shared__ int cur[512];
    __shared__ int buf[512];
    __shared__ int lcsr[CAP];

    const int t = threadIdx.x;
    const int b = blockIdx.x;
    const int s0 = bstart[b], s1 = bstart[b + 1];
    const int n = s1 - s0;

    cnts[t] = 0;
    __syncthreads();
    for (int i = t; i < n; i += 512)
        atomicAdd(&cnts[binned[s0 + i] & BMASK], 1);
    __syncthreads();

    // exclusive scan over 512
    {
        const int v = cnts[t];
        buf[t] = v; __syncthreads();
        for (int o = 1; o < 512; o <<= 1) {
            const int a = (t >= o) ? buf[t - o] : 0;
            __syncthreads();
            buf[t] += a;
            __syncthreads();
        }
        cur[t] = buf[t] - v;   // exclusive prefix
        const int node = (b << BSHIFT) + t;
        if (node < N_NODES) row_start[node] = s0 + cur[t];
        if (b == NB - 1 && t == 0) row_start[N_NODES] = N_EDGES;
    }
    __syncthreads();

    for (int i = t; i < n; i += 512) {
        const int v = binned[s0 + i];
        const int p = atomicAdd(&cur[v & BMASK], 1);
        lcsr[p] = v >> BSHIFT;
    }
    __syncthreads();

    for (int i = t; i < n; i += 512) binned[s0 + i] = lcsr[i];
}

// ============================== Fused AGNN gather ===========================
// 16 lanes per dst node; lane l owns feature l. xn rows are bf16 (32 B) so
// the whole gather set (3.6 MB) is L2-resident per XCD. Lane g computes edge
// g's cosine logit; (w*norm[src], src) broadcast via __shfl; lane l
// accumulates its feature via L1/L2-hot bf16 scalar loads. h never
// materialized (h = xn*norm). No atomics.
template <int EMIT_NORMED>
__global__ __launch_bounds__(256) void k_agnn(const int* __restrict__ row_start,
                                              const int* __restrict__ csr_src,
                                              const unsigned short* __restrict__ xnb,
                                              const float* __restrict__ normv,
                                              const float* __restrict__ betap,
                                              float* __restrict__ outf,
                                              unsigned short* __restrict__ outb,
                                              float* __restrict__ out_norm) {
    const int l16  = threadIdx.x & 15;
    const int node = (blockIdx.x * 256 + threadIdx.x) >> 4;   // grid exact
    const float beta  = betap ? betap[0] : 1.0f;
    const float shift = fabsf(beta);

    const int rs = row_start[node];
    const int re = row_start[node + 1];

    // dst row: 2x16B bf16 loads -> 16 f32 regs
    const bf16x8* xd = (const bf16x8*)(xnb + (size_t)node * HID);
    const bf16x8 dlo = xd[0], dhi = xd[1];
    float dd[16];
#pragma unroll
    for (int i = 0; i < 8; i++) {
        dd[i]     = bf2f((unsigned short)dlo[i]);
        dd[i + 8] = bf2f((unsigned short)dhi[i]);
    }

    const unsigned short* colb = xnb + l16;   // lane's feature column base
    float acc0 = 0.f, acc1 = 0.f, sw = 0.f;

    for (int t = rs; t < re; t += 16) {
        const int k = t + l16;
        const bool ok = (k < re);
        const int sidx = ok ? csr_src[k] : 0;
        const bf16x8* xs = (const bf16x8*)(xnb + (size_t)sidx * HID);
        const bf16x8 slo = xs[0], shi = xs[1];
        const float nj = normv[sidx];
        float dot = 0.f;
#pragma unroll
        for (int i = 0; i < 8; i++) {
            dot += bf2f((unsigned short)slo[i]) * dd[i];
            dot += bf2f((unsigned short)shi[i]) * dd[i + 8];
        }
        const float w = ok ? __expf(beta * dot - shift) : 0.f;

        // group weight sum
        float ws = w;
        ws += __shfl_xor(ws, 1); ws += __shfl_xor(ws, 2);
        ws += __shfl_xor(ws, 4); ws += __shfl_xor(ws, 8);
        sw += ws;

        const float wn = w * nj;         // fold ||h_src|| into the weight
#pragma unroll
        for (int j = 0; j < 16; j += 2) {
            const float w0 = __shfl(wn, j, 16);
            const int   s0i = __shfl(sidx, j, 16);
            const float w1 = __shfl(wn, j + 1, 16);
            const int   s1i = __shfl(sidx, j + 1, 16);
            acc0 += w0 * bf2f(colb[(size_t)s0i * HID]);
            acc1 += w1 * bf2f(colb[(size_t)s1i * HID]);
        }
    }

    const float v = (acc0 + acc1) / fmaxf(sw, 1e-16f);
    if (EMIT_NORMED) {
        float ss = v * v;
        ss += __shfl_xor(ss, 1); ss += __shfl_xor(ss, 2);
        ss += __shfl_xor(ss, 4); ss += __shfl_xor(ss, 8);
        const float nrm = sqrtf(ss);
        const float rn  = 1.f / fmaxf(nrm, 1e-12f);
        outb[(size_t)node * HID + l16] = f2bf_rtn(v * rn);
        if (l16 == 0) out_norm[node] = nrm;
    } else {
        outf[(size_t)node * HID + l16] = v;
    }
}

// ============================== Stage 3 =====================================
__global__ __launch_bounds__(256) void k_lin2(const float* __restrict__ h,
                                              const float* __restrict__ w2,
                                              const float* __restrict__ b2,
                                              float* __restrict__ out) {
    __shared__ float w2s[N_CLASS][HID];
    __shared__ float b2s[N_CLASS];
    for (int i = threadIdx.x; i < N_CLASS * HID; i += 256)
        ((float*)w2s)[i] = w2[i];
    if (threadIdx.x < N_CLASS) b2s[threadIdx.x] = b2[threadIdx.x];
    __syncthreads();

    const int n = blockIdx.x * 256 + threadIdx.x;
    if (n >= N_NODES) return;

    float hv[HID];
    const float4* hr = (const float4*)(h + (size_t)n * HID);
#pragma unroll
    for (int q = 0; q < 4; q++) {
        const float4 v = hr[q];
        hv[q*4+0]=v.x; hv[q*4+1]=v.y; hv[q*4+2]=v.z; hv[q*4+3]=v.w;
    }

    float lg[N_CLASS];
    float m = -3.0e38f;
#pragma unroll
    for (int j = 0; j < N_CLASS; j++) {
        float acc = b2s[j];
#pragma unroll
        for (int k = 0; k < HID; k++) acc += hv[k] * w2s[j][k];
        lg[j] = acc;
        m = fmaxf(m, acc);
    }
    float sum = 0.f;
#pragma unroll
    for (int j = 0; j < N_CLASS; j++) sum += __expf(lg[j] - m);
    const float lse = m + __logf(sum);

    float4* orow = (float4*)(out + (size_t)n * N_CLASS);
#pragma unroll
    for (int q = 0; q < N_CLASS / 4; q++) {
        float4 o;
        o.x = lg[q*4+0] - lse;
        o.y = lg[q*4+1] - lse;
        o.z = lg[q*4+2] - lse;
        o.w = lg[q*4+3] - lse;
        orow[q] = o;
    }
}

// ============================== Launch ======================================
extern "C" void kernel_launch(void* const* d_in, const int* in_sizes, int n_in,
                              void* d_out, int out_size, void* d_ws, size_t ws_size,
                              hipStream_t stream) {
    const float* x     = (const float*)d_in[0];
    const int*   ei    = (const int*)  d_in[1];   // [2][E]: row0=src, row1=dst
    const float* w1    = (const float*)d_in[2];
    const float* b1    = (const float*)d_in[3];
    const float* beta2 = (const float*)d_in[4];
    const float* w2    = (const float*)d_in[5];
    const float* b2    = (const float*)d_in[6];
    float* out = (float*)d_out;

    const int* srcp = ei;
    const int* dstp = ei + N_EDGES;

    // workspace layout
    unsigned short* xnb1 = (unsigned short*)d_ws;        // [N,16] bf16 unit rows
    unsigned short* xnb2 = xnb1 + (size_t)N_NODES * HID; // [N,16] bf16
    float* norm1 = (float*)(xnb2 + (size_t)N_NODES * HID); // [N]
    float* norm2 = norm1 + N_NODES;                      // [N]
    float* hF    = norm2 + N_NODES;                      // [N,16] f32 final
    int* row_start = (int*)(hF + (size_t)N_NODES * HID); // [N+1]
    int* gcount    = row_start + N_NODES + 1;            // [NB]
    int* bstart    = gcount + NB;                        // [NB+1]
    int* cursor    = bstart + NB + 1;                    // [NB]
    int* binned    = cursor + NB;                        // [E] packed, then csr

    const int nodeGrid = (N_NODES + 255) / 256;        // 391
    const int lin1Grid = (NT + 3) / 4;                 // 1563 (4 waves/block)
    const int binGrid  = (N_EDGES + EPB - 1) / EPB;    // 782
    const int agnnGrid = N_NODES * HID / 256;          // 6250

    // ---- CSR build: coalesced two-level binning ----
    k_zero <<<1,       256, 0, stream>>>(gcount, NB);
    k_bhist<<<binGrid, 256, 0, stream>>>(dstp, gcount);
    k_bscan<<<1,       256, 0, stream>>>(gcount, bstart, cursor);
    k_bin  <<<binGrid, 256, 0, stream>>>(srcp, dstp, cursor, binned);
    k_csr  <<<NB,      512, 0, stream>>>(bstart, binned, row_start);

    // ---- network (norms fused into producers; xn rows bf16/L2-resident) ----
    k_lin1<<<lin1Grid, 256, 0, stream>>>(x, w1, b1, xnb1, norm1);

    k_agnn<1><<<agnnGrid, 256, 0, stream>>>(row_start, binned, xnb1, norm1,
                                            nullptr, nullptr, xnb2, norm2);
    k_agnn<0><<<agnnGrid, 256, 0, stream>>>(row_start, binned, xnb2, norm2,
                                            beta2, hF, nullptr, nullptr);

    k_lin2<<<nodeGrid, 256, 0, stream>>>(hF, w2, b2, out);
}

// Round 9
// 211.996 us; speedup vs baseline: 1.8059x; 1.2064x over previous
//
#include <hip/hip_runtime.h>

#define N_NODES 100000
#define N_EDGES 3200000
#define N_FEAT  512
#define HID     16
#define N_CLASS 40

#define BSHIFT  9                      // 512 nodes per bucket
#define BMASK   ((1 << BSHIFT) - 1)
#define NB      196                    // ceil(100000 / 512)
#define CAP     18432                  // padded bucket region (mean 16384, +16 sigma)
#define EPB     4096                   // edges per binning block

typedef __attribute__((ext_vector_type(8))) short bf16x8;
typedef __attribute__((ext_vector_type(4))) float f32x4;

// exact split: v == hi_f32 + lo_residual; hi = truncated-top-16 (exact),
// lo = bf16(v - hi) (residual <= 2^-8 |v|, its bf16 trunc err <= 2^-16 |v|)
__device__ inline short2 split_bf(float v) {
    const unsigned u = __float_as_uint(v);
    const short hi = (short)(u >> 16);
    const float hf = __uint_as_float(u & 0xFFFF0000u);
    const short lo = (short)(__float_as_uint(v - hf) >> 16);
    return make_short2(hi, lo);
}

// round-to-nearest-even bf16 (half the error of truncation)
__device__ inline unsigned short f2bf_rtn(float v) {
    unsigned u = __float_as_uint(v);
    u += 0x7FFFu + ((u >> 16) & 1u);
    return (unsigned short)(u >> 16);
}
__device__ inline float bf2f(unsigned short u) {
    return __uint_as_float(((unsigned)u) << 16);
}

// ============================== Stage 1 (MFMA) ==============================
// xnb = bf16(rownorm(relu(x @ W1^T + b1))), norm = ||row||, fused epilogue.
#define NT (N_NODES / 16)              // 6250 tiles
__global__ __launch_bounds__(256) void k_lin1(const float* __restrict__ x,
                                              const float* __restrict__ w1,
                                              const float* __restrict__ b1,
                                              unsigned short* __restrict__ xnb,
                                              float* __restrict__ normv) {
    // B-fragment layout: frag f = (kt, lane): col=lane&15, k=kt*32+(lane>>4)*8
    __shared__ __align__(16) short bfH[16 * 64 * 8];   // 16 KB
    __shared__ __align__(16) short bfL[16 * 64 * 8];   // 16 KB

    const int t = threadIdx.x;
    for (int f = t; f < 16 * 64; f += 256) {
        const int kt  = f >> 6;
        const int ln  = f & 63;
        const int col = ln & 15;
        const int k0  = kt * 32 + (ln >> 4) * 8;
        const float4 v0 = *(const float4*)(w1 + col * N_FEAT + k0);
        const float4 v1 = *(const float4*)(w1 + col * N_FEAT + k0 + 4);
        bf16x8 hh, ll;
        short2 r;
        r = split_bf(v0.x); hh[0] = r.x; ll[0] = r.y;
        r = split_bf(v0.y); hh[1] = r.x; ll[1] = r.y;
        r = split_bf(v0.z); hh[2] = r.x; ll[2] = r.y;
        r = split_bf(v0.w); hh[3] = r.x; ll[3] = r.y;
        r = split_bf(v1.x); hh[4] = r.x; ll[4] = r.y;
        r = split_bf(v1.y); hh[5] = r.x; ll[5] = r.y;
        r = split_bf(v1.z); hh[6] = r.x; ll[6] = r.y;
        r = split_bf(v1.w); hh[7] = r.x; ll[7] = r.y;
        ((bf16x8*)bfH)[f] = hh;
        ((bf16x8*)bfL)[f] = ll;
    }
    __syncthreads();

    const int wv   = t >> 6;
    const int l    = t & 63;
    const int tile = blockIdx.x * 4 + wv;
    if (tile >= NT) return;

    const int r0 = tile * 16;
    const float* xp = x + (size_t)(r0 + (l & 15)) * N_FEAT + ((l >> 4) * 8);

    f32x4 acc = {0.f, 0.f, 0.f, 0.f};
    float4 c0 = *(const float4*)(xp);
    float4 c1 = *(const float4*)(xp + 4);
#pragma unroll
    for (int kt = 0; kt < 16; ++kt) {
        float4 n0, n1;
        if (kt < 15) {
            n0 = *(const float4*)(xp + (kt + 1) * 32);
            n1 = *(const float4*)(xp + (kt + 1) * 32 + 4);
        }
        bf16x8 ah, al;
        short2 r;
        r = split_bf(c0.x); ah[0] = r.x; al[0] = r.y;
        r = split_bf(c0.y); ah[1] = r.x; al[1] = r.y;
        r = split_bf(c0.z); ah[2] = r.x; al[2] = r.y;
        r = split_bf(c0.w); ah[3] = r.x; al[3] = r.y;
        r = split_bf(c1.x); ah[4] = r.x; al[4] = r.y;
        r = split_bf(c1.y); ah[5] = r.x; al[5] = r.y;
        r = split_bf(c1.z); ah[6] = r.x; al[6] = r.y;
        r = split_bf(c1.w); ah[7] = r.x; al[7] = r.y;
        const bf16x8 bh = ((const bf16x8*)bfH)[kt * 64 + l];
        const bf16x8 bl = ((const bf16x8*)bfL)[kt * 64 + l];
        acc = __builtin_amdgcn_mfma_f32_16x16x32_bf16(ah, bh, acc, 0, 0, 0);
        acc = __builtin_amdgcn_mfma_f32_16x16x32_bf16(al, bh, acc, 0, 0, 0);
        acc = __builtin_amdgcn_mfma_f32_16x16x32_bf16(ah, bl, acc, 0, 0, 0);
        c0 = n0; c1 = n1;
    }

    // C/D: col = lane&15, row = (lane>>4)*4 + reg. Fused relu + row-normalize.
    const float bias = b1[l & 15];
#pragma unroll
    for (int r = 0; r < 4; ++r) {
        const float v = fmaxf(acc[r] + bias, 0.f);
        float ss = v * v;
        ss += __shfl_xor(ss, 1); ss += __shfl_xor(ss, 2);
        ss += __shfl_xor(ss, 4); ss += __shfl_xor(ss, 8);
        const float nrm = sqrtf(ss);
        const float rn  = 1.f / fmaxf(nrm, 1e-12f);
        const int row = r0 + (l >> 4) * 4 + r;
        xnb[(size_t)row * HID + (l & 15)] = f2bf_rtn(v * rn);
        if ((l & 15) == 0) normv[row] = nrm;
    }
}

// ============================== CSR build (padded buckets) ==================
// cursor[b] starts at b*CAP; buckets live in fixed regions -> no pre-histogram.
__global__ __launch_bounds__(256) void k_init(int* __restrict__ cursor) {
    const int i = threadIdx.x;
    if (i < NB) cursor[i] = i * CAP;
}

// group EPB edges by bucket in LDS, reserve contiguous chunks, flush coalesced.
// binned[] entry = (src << 9) | (dst & 511), grouped by bucket.
__global__ __launch_bounds__(256) void k_bin(const int* __restrict__ src,
                                             const int* __restrict__ dst,
                                             int* __restrict__ cursor,
                                             int* __restrict__ binned) {
    __shared__ int hist[NB];
    __shared__ int lofs[NB];
    __shared__ int base[NB];
    __shared__ int rk[NB];
    __shared__ int buf[256];
    __shared__ int stage[EPB];
    __shared__ unsigned short sbkt[EPB];

    const int t = threadIdx.x;
    for (int i = t; i < NB; i += 256) { hist[i] = 0; rk[i] = 0; }
    __syncthreads();

    const int e0 = blockIdx.x * EPB;
    int bk[EPB / 256];
    int vv[EPB / 256];
#pragma unroll
    for (int k = 0; k < EPB / 256; k++) {
        const int e = e0 + k * 256 + t;
        if (e < N_EDGES) {
            const int d = dst[e], s = src[e];
            bk[k] = d >> BSHIFT;
            vv[k] = (s << BSHIFT) | (d & BMASK);
            atomicAdd(&hist[bk[k]], 1);
        } else bk[k] = -1;
    }
    __syncthreads();

    // exclusive scan hist -> lofs
    {
        const int v = (t < NB) ? hist[t] : 0;
        buf[t] = v; __syncthreads();
        for (int o = 1; o < 256; o <<= 1) {
            const int a = (t >= o) ? buf[t - o] : 0;
            __syncthreads();
            buf[t] += a;
            __syncthreads();
        }
        if (t < NB) lofs[t] = buf[t] - v;
    }
    // reserve global chunk per bucket (cursor pre-set to b*CAP)
    if (t < NB && hist[t] > 0) base[t] = atomicAdd(&cursor[t], hist[t]);

    // local scatter into stage (grouped by bucket)
#pragma unroll
    for (int k = 0; k < EPB / 256; k++) {
        if (bk[k] >= 0) {
            const int r = atomicAdd(&rk[bk[k]], 1);
            const int slot = lofs[bk[k]] + r;
            stage[slot] = vv[k];
            sbkt[slot] = (unsigned short)bk[k];
        }
    }
    __syncthreads();

    // flush: consecutive slots of a bucket -> consecutive global addresses
    const int nloc = min(EPB, N_EDGES - e0);
    for (int s2 = t; s2 < nloc; s2 += 256) {
        const int b = sbkt[s2];
        binned[base[b] + (s2 - lofs[b])] = stage[s2];
    }
}

// per bucket: counts per node, scan -> row_start/row_cnt, sort srcs in LDS,
// write csr coalesced IN-PLACE over binned (per-block region).
__global__ __launch_bounds__(512) void k_csr(const int* __restrict__ cursor,
                                             int* __restrict__ binned,
                                             int* __restrict__ row_start,
                                             unsigned short* __restrict__ row_cnt) {
    __shared__ int cnts[512];
    __shared__ int cur[512];
    __shared__ int buf[512];
    __shared__ int lcsr[CAP];

    const int t = threadIdx.x;
    const int b = blockIdx.x;
    const int s0 = b * CAP;
    const int n = cursor[b] - s0;        // fill level of this bucket

    cnts[t] = 0;
    __syncthreads();
    for (int i = t; i < n; i += 512)
        atomicAdd(&cnts[binned[s0 + i] & BMASK], 1);
    __syncthreads();

    // exclusive scan over 512
    {
        const int v = cnts[t];
        buf[t] = v; __syncthreads();
        for (int o = 1; o < 512; o <<= 1) {
            const int a = (t >= o) ? buf[t - o] : 0;
            __syncthreads();
            buf[t] += a;
            __syncthreads();
        }
        cur[t] = buf[t] - v;   // exclusive prefix
        const int node = (b << BSHIFT) + t;
        if (node < N_NODES) {
            row_start[node] = s0 + cur[t];
            row_cnt[node]   = (unsigned short)v;
        }
    }
    __syncthreads();

    for (int i = t; i < n; i += 512) {
        const int v = binned[s0 + i];
        const int p = atomicAdd(&cur[v & BMASK], 1);
        lcsr[p] = v >> BSHIFT;
    }
    __syncthreads();

    for (int i = t; i < n; i += 512) binned[s0 + i] = lcsr[i];
}

// ============================== Fused AGNN gather ===========================
// 16 lanes per dst node; lane l owns feature l. bf16 xn rows (32 B): whole
// gather set (3.6 MB) is L2-resident. No atomics.
template <int EMIT_NORMED>
__global__ __launch_bounds__(256) void k_agnn(const int* __restrict__ row_start,
                                              const unsigned short* __restrict__ row_cnt,
                                              const int* __restrict__ csr_src,
                                              const unsigned short* __restrict__ xnb,
                                              const float* __restrict__ normv,
                                              const float* __restrict__ betap,
                                              float* __restrict__ outf,
                                              unsigned short* __restrict__ outb,
                                              float* __restrict__ out_norm) {
    const int l16  = threadIdx.x & 15;
    const int node = (blockIdx.x * 256 + threadIdx.x) >> 4;   // grid exact
    const float beta  = betap ? betap[0] : 1.0f;
    const float shift = fabsf(beta);

    const int rs  = row_start[node];
    const int cnt = row_cnt[node];

    // dst row: 2x16B bf16 loads -> 16 f32 regs
    const bf16x8* xd = (const bf16x8*)(xnb + (size_t)node * HID);
    const bf16x8 dlo = xd[0], dhi = xd[1];
    float dd[16];
#pragma unroll
    for (int i = 0; i < 8; i++) {
        dd[i]     = bf2f((unsigned short)dlo[i]);
        dd[i + 8] = bf2f((unsigned short)dhi[i]);
    }

    const unsigned short* colb = xnb + l16;   // lane's feature column base
    float acc0 = 0.f, acc1 = 0.f, sw = 0.f;

    for (int t = 0; t < cnt; t += 16) {
        const int k = t + l16;
        const bool ok = (k < cnt);
        const int sidx = ok ? csr_src[rs + k] : 0;
        const bf16x8* xs = (const bf16x8*)(xnb + (size_t)sidx * HID);
        const bf16x8 slo = xs[0], shi = xs[1];
        const float nj = normv[sidx];
        float dot = 0.f;
#pragma unroll
        for (int i = 0; i < 8; i++) {
            dot += bf2f((unsigned short)slo[i]) * dd[i];
            dot += bf2f((unsigned short)shi[i]) * dd[i + 8];
        }
        const float w = ok ? __expf(beta * dot - shift) : 0.f;

        // group weight sum
        float ws = w;
        ws += __shfl_xor(ws, 1); ws += __shfl_xor(ws, 2);
        ws += __shfl_xor(ws, 4); ws += __shfl_xor(ws, 8);
        sw += ws;

        const float wn = w * nj;         // fold ||h_src|| into the weight
#pragma unroll
        for (int j = 0; j < 16; j += 2) {
            const float w0 = __shfl(wn, j, 16);
            const int   s0i = __shfl(sidx, j, 16);
            const float w1 = __shfl(wn, j + 1, 16);
            const int   s1i = __shfl(sidx, j + 1, 16);
            acc0 += w0 * bf2f(colb[(size_t)s0i * HID]);
            acc1 += w1 * bf2f(colb[(size_t)s1i * HID]);
        }
    }

    const float v = (acc0 + acc1) / fmaxf(sw, 1e-16f);
    if (EMIT_NORMED) {
        float ss = v * v;
        ss += __shfl_xor(ss, 1); ss += __shfl_xor(ss, 2);
        ss += __shfl_xor(ss, 4); ss += __shfl_xor(ss, 8);
        const float nrm = sqrtf(ss);
        const float rn  = 1.f / fmaxf(nrm, 1e-12f);
        outb[(size_t)node * HID + l16] = f2bf_rtn(v * rn);
        if (l16 == 0) out_norm[node] = nrm;
    } else {
        outf[(size_t)node * HID + l16] = v;
    }
}

// ============================== Stage 3 =====================================
__global__ __launch_bounds__(256) void k_lin2(const float* __restrict__ h,
                                              const float* __restrict__ w2,
                                              const float* __restrict__ b2,
                                              float* __restrict__ out) {
    __shared__ float w2s[N_CLASS][HID];
    __shared__ float b2s[N_CLASS];
    for (int i = threadIdx.x; i < N_CLASS * HID; i += 256)
        ((float*)w2s)[i] = w2[i];
    if (threadIdx.x < N_CLASS) b2s[threadIdx.x] = b2[threadIdx.x];
    __syncthreads();

    const int n = blockIdx.x * 256 + threadIdx.x;
    if (n >= N_NODES) return;

    float hv[HID];
    const float4* hr = (const float4*)(h + (size_t)n * HID);
#pragma unroll
    for (int q = 0; q < 4; q++) {
        const float4 v = hr[q];
        hv[q*4+0]=v.x; hv[q*4+1]=v.y; hv[q*4+2]=v.z; hv[q*4+3]=v.w;
    }

    float lg[N_CLASS];
    float m = -3.0e38f;
#pragma unroll
    for (int j = 0; j < N_CLASS; j++) {
        float acc = b2s[j];
#pragma unroll
        for (int k = 0; k < HID; k++) acc += hv[k] * w2s[j][k];
        lg[j] = acc;
        m = fmaxf(m, acc);
    }
    float sum = 0.f;
#pragma unroll
    for (int j = 0; j < N_CLASS; j++) sum += __expf(lg[j] - m);
    const float lse = m + __logf(sum);

    float4* orow = (float4*)(out + (size_t)n * N_CLASS);
#pragma unroll
    for (int q = 0; q < N_CLASS / 4; q++) {
        float4 o;
        o.x = lg[q*4+0] - lse;
        o.y = lg[q*4+1] - lse;
        o.z = lg[q*4+2] - lse;
        o.w = lg[q*4+3] - lse;
        orow[q] = o;
    }
}

// ============================== Launch ======================================
extern "C" void kernel_launch(void* const* d_in, const int* in_sizes, int n_in,
                              void* d_out, int out_size, void* d_ws, size_t ws_size,
                              hipStream_t stream) {
    const float* x     = (const float*)d_in[0];
    const int*   ei    = (const int*)  d_in[1];   // [2][E]: row0=src, row1=dst
    const float* w1    = (const float*)d_in[2];
    const float* b1    = (const float*)d_in[3];
    const float* beta2 = (const float*)d_in[4];
    const float* w2    = (const float*)d_in[5];
    const float* b2    = (const float*)d_in[6];
    float* out = (float*)d_out;

    const int* srcp = ei;
    const int* dstp = ei + N_EDGES;

    // workspace layout (~28.8 MB)
    unsigned short* xnb1 = (unsigned short*)d_ws;        // [N,16] bf16 unit rows
    unsigned short* xnb2 = xnb1 + (size_t)N_NODES * HID; // [N,16] bf16
    float* norm1 = (float*)(xnb2 + (size_t)N_NODES * HID); // [N]
    float* norm2 = norm1 + N_NODES;                      // [N]
    float* hF    = norm2 + N_NODES;                      // [N,16] f32 final
    int* row_start = (int*)(hF + (size_t)N_NODES * HID); // [N]
    unsigned short* row_cnt = (unsigned short*)(row_start + N_NODES); // [N]
    int* cursor = (int*)(row_cnt + N_NODES + (N_NODES & 1)); // [NB]
    int* binned = cursor + NB + 2;                       // [NB*CAP] padded

    const int nodeGrid = (N_NODES + 255) / 256;        // 391
    const int lin1Grid = (NT + 3) / 4;                 // 1563 (4 waves/block)
    const int binGrid  = (N_EDGES + EPB - 1) / EPB;    // 782
    const int agnnGrid = N_NODES * HID / 256;          // 6250

    // ---- CSR build: padded buckets, no pre-histogram ----
    k_init<<<1,       256, 0, stream>>>(cursor);
    k_bin <<<binGrid, 256, 0, stream>>>(srcp, dstp, cursor, binned);
    k_csr <<<NB,      512, 0, stream>>>(cursor, binned, row_start, row_cnt);

    // ---- network (norms fused into producers; xn rows bf16/L2-resident) ----
    k_lin1<<<lin1Grid, 256, 0, stream>>>(x, w1, b1, xnb1, norm1);

    k_agnn<1><<<agnnGrid, 256, 0, stream>>>(row_start, row_cnt, binned, xnb1,
                                            norm1, nullptr, nullptr, xnb2, norm2);
    k_agnn<0><<<agnnGrid, 256, 0, stream>>>(row_start, row_cnt, binned, xnb2,
                                            norm2, beta2, hF, nullptr, nullptr);

    k_lin2<<<nodeGrid, 256, 0, stream>>>(hF, w2, b2, out);
}

// Round 10
// 199.087 us; speedup vs baseline: 1.9230x; 1.0648x over previous
//
#include <hip/hip_runtime.h>

#define N_NODES 100000
#define N_EDGES 3200000
#define N_FEAT  512
#define HID     16
#define N_CLASS 40

#define BSHIFT  9                      // 512 nodes per bucket
#define BMASK   ((1 << BSHIFT) - 1)
#define NB      196                    // ceil(100000 / 512)
#define CAP     18432                  // padded bucket region (mean 16384, +16 sigma)
#define EPB     4096                   // edges per binning block

#define BIN_BLOCKS  ((N_EDGES + EPB - 1) / EPB)   // 782
#define NT          (N_NODES / 16)                // 6250 lin1 tiles
#define LIN1_BLOCKS ((NT + 3) / 4)                // 1563

typedef __attribute__((ext_vector_type(8))) short bf16x8;
typedef __attribute__((ext_vector_type(4))) float f32x4;

// exact split: v == hi_f32 + lo_residual; hi = truncated-top-16 (exact),
// lo = bf16(v - hi)
__device__ inline short2 split_bf(float v) {
    const unsigned u = __float_as_uint(v);
    const short hi = (short)(u >> 16);
    const float hf = __uint_as_float(u & 0xFFFF0000u);
    const short lo = (short)(__float_as_uint(v - hf) >> 16);
    return make_short2(hi, lo);
}
__device__ inline unsigned short f2bf_rtn(float v) {
    unsigned u = __float_as_uint(v);
    u += 0x7FFFu + ((u >> 16) & 1u);
    return (unsigned short)(u >> 16);
}
__device__ inline float bf2f(unsigned short u) {
    return __uint_as_float(((unsigned)u) << 16);
}

// ================= Fused: CSR binning (blocks 0..781) + lin1 (rest) =========
// Independent pipelines share one dispatch so the latency-bound binning hides
// under the HBM-bound lin1 stream. LDS unioned: bin 28.7 KB, lin1 32 KB.
struct BinSmem {
    int hist[NB]; int lofs[NB]; int base[NB]; int rk[NB];
    int buf[256]; int stage[EPB]; unsigned short sbkt[EPB];
};
struct Lin1Smem { short bfH[16 * 64 * 8]; short bfL[16 * 64 * 8]; };

__device__ void bin_body(char* smemraw,
                         const int* __restrict__ src,
                         const int* __restrict__ dst,
                         int* __restrict__ cursor,
                         int* __restrict__ binned) {
    BinSmem& sm = *(BinSmem*)smemraw;
    const int t = threadIdx.x;
    for (int i = t; i < NB; i += 256) { sm.hist[i] = 0; sm.rk[i] = 0; }
    __syncthreads();

    const int e0 = blockIdx.x * EPB;
    int bk[EPB / 256];
    int vv[EPB / 256];
#pragma unroll
    for (int k = 0; k < EPB / 256; k++) {
        const int e = e0 + k * 256 + t;
        if (e < N_EDGES) {
            const int d = dst[e], s = src[e];
            bk[k] = d >> BSHIFT;
            vv[k] = (s << BSHIFT) | (d & BMASK);
            atomicAdd(&sm.hist[bk[k]], 1);
        } else bk[k] = -1;
    }
    __syncthreads();

    // exclusive scan hist -> lofs
    {
        const int v = (t < NB) ? sm.hist[t] : 0;
        sm.buf[t] = v; __syncthreads();
        for (int o = 1; o < 256; o <<= 1) {
            const int a = (t >= o) ? sm.buf[t - o] : 0;
            __syncthreads();
            sm.buf[t] += a;
            __syncthreads();
        }
        if (t < NB) sm.lofs[t] = sm.buf[t] - v;
    }
    // reserve global chunk per bucket (cursor zero-initialized; region b*CAP)
    if (t < NB && sm.hist[t] > 0)
        sm.base[t] = t * CAP + atomicAdd(&cursor[t], sm.hist[t]);

    // local scatter into stage (grouped by bucket)
#pragma unroll
    for (int k = 0; k < EPB / 256; k++) {
        if (bk[k] >= 0) {
            const int r = atomicAdd(&sm.rk[bk[k]], 1);
            const int slot = sm.lofs[bk[k]] + r;
            sm.stage[slot] = vv[k];
            sm.sbkt[slot] = (unsigned short)bk[k];
        }
    }
    __syncthreads();

    // flush: consecutive slots of a bucket -> consecutive global addresses
    const int nloc = min(EPB, N_EDGES - e0);
    for (int s2 = t; s2 < nloc; s2 += 256) {
        const int b = sm.sbkt[s2];
        binned[sm.base[b] + (s2 - sm.lofs[b])] = sm.stage[s2];
    }
}

__device__ void lin1_body(char* smemraw, int lblk,
                          const float* __restrict__ x,
                          const float* __restrict__ w1,
                          const float* __restrict__ b1,
                          unsigned short* __restrict__ xnb,
                          float* __restrict__ normv) {
    Lin1Smem& sm = *(Lin1Smem*)smemraw;
    const int t = threadIdx.x;
    for (int f = t; f < 16 * 64; f += 256) {
        const int kt  = f >> 6;
        const int ln  = f & 63;
        const int col = ln & 15;
        const int k0  = kt * 32 + (ln >> 4) * 8;
        const float4 v0 = *(const float4*)(w1 + col * N_FEAT + k0);
        const float4 v1 = *(const float4*)(w1 + col * N_FEAT + k0 + 4);
        bf16x8 hh, ll;
        short2 r;
        r = split_bf(v0.x); hh[0] = r.x; ll[0] = r.y;
        r = split_bf(v0.y); hh[1] = r.x; ll[1] = r.y;
        r = split_bf(v0.z); hh[2] = r.x; ll[2] = r.y;
        r = split_bf(v0.w); hh[3] = r.x; ll[3] = r.y;
        r = split_bf(v1.x); hh[4] = r.x; ll[4] = r.y;
        r = split_bf(v1.y); hh[5] = r.x; ll[5] = r.y;
        r = split_bf(v1.z); hh[6] = r.x; ll[6] = r.y;
        r = split_bf(v1.w); hh[7] = r.x; ll[7] = r.y;
        ((bf16x8*)sm.bfH)[f] = hh;
        ((bf16x8*)sm.bfL)[f] = ll;
    }
    __syncthreads();

    const int wv   = t >> 6;
    const int l    = t & 63;
    const int tile = lblk * 4 + wv;
    if (tile >= NT) return;

    const int r0 = tile * 16;
    const float* xp = x + (size_t)(r0 + (l & 15)) * N_FEAT + ((l >> 4) * 8);

    f32x4 acc = {0.f, 0.f, 0.f, 0.f};
    float4 c0 = *(const float4*)(xp);
    float4 c1 = *(const float4*)(xp + 4);
#pragma unroll
    for (int kt = 0; kt < 16; ++kt) {
        float4 n0, n1;
        if (kt < 15) {
            n0 = *(const float4*)(xp + (kt + 1) * 32);
            n1 = *(const float4*)(xp + (kt + 1) * 32 + 4);
        }
        bf16x8 ah, al;
        short2 r;
        r = split_bf(c0.x); ah[0] = r.x; al[0] = r.y;
        r = split_bf(c0.y); ah[1] = r.x; al[1] = r.y;
        r = split_bf(c0.z); ah[2] = r.x; al[2] = r.y;
        r = split_bf(c0.w); ah[3] = r.x; al[3] = r.y;
        r = split_bf(c1.x); ah[4] = r.x; al[4] = r.y;
        r = split_bf(c1.y); ah[5] = r.x; al[5] = r.y;
        r = split_bf(c1.z); ah[6] = r.x; al[6] = r.y;
        r = split_bf(c1.w); ah[7] = r.x; al[7] = r.y;
        const bf16x8 bh = ((const bf16x8*)sm.bfH)[kt * 64 + l];
        const bf16x8 bl = ((const bf16x8*)sm.bfL)[kt * 64 + l];
        acc = __builtin_amdgcn_mfma_f32_16x16x32_bf16(ah, bh, acc, 0, 0, 0);
        acc = __builtin_amdgcn_mfma_f32_16x16x32_bf16(al, bh, acc, 0, 0, 0);
        acc = __builtin_amdgcn_mfma_f32_16x16x32_bf16(ah, bl, acc, 0, 0, 0);
        c0 = n0; c1 = n1;
    }

    const float bias = b1[l & 15];
#pragma unroll
    for (int r = 0; r < 4; ++r) {
        const float v = fmaxf(acc[r] + bias, 0.f);
        float ss = v * v;
        ss += __shfl_xor(ss, 1); ss += __shfl_xor(ss, 2);
        ss += __shfl_xor(ss, 4); ss += __shfl_xor(ss, 8);
        const float nrm = sqrtf(ss);
        const float rn  = 1.f / fmaxf(nrm, 1e-12f);
        const int row = r0 + (l >> 4) * 4 + r;
        xnb[(size_t)row * HID + (l & 15)] = f2bf_rtn(v * rn);
        if ((l & 15) == 0) normv[row] = nrm;
    }
}

__global__ __launch_bounds__(256) void k_bin_lin1(const int* __restrict__ src,
                                                  const int* __restrict__ dst,
                                                  int* __restrict__ cursor,
                                                  int* __restrict__ binned,
                                                  const float* __restrict__ x,
                                                  const float* __restrict__ w1,
                                                  const float* __restrict__ b1,
                                                  unsigned short* __restrict__ xnb,
                                                  float* __restrict__ normv) {
    __shared__ __align__(16) char smem[sizeof(Lin1Smem) > sizeof(BinSmem)
                                       ? sizeof(Lin1Smem) : sizeof(BinSmem)];
    if (blockIdx.x < BIN_BLOCKS)
        bin_body(smem, src, dst, cursor, binned);
    else
        lin1_body(smem, blockIdx.x - BIN_BLOCKS, x, w1, b1, xnb, normv);
}

// ============================== k_csr =======================================
// per bucket: counts per node, scan -> row_start/row_cnt, sort srcs in LDS,
// write csr coalesced IN-PLACE over binned (per-block region).
__global__ __launch_bounds__(512) void k_csr(const int* __restrict__ cursor,
                                             int* __restrict__ binned,
                                             int* __restrict__ row_start,
                                             unsigned short* __restrict__ row_cnt) {
    __shared__ int cnts[512];
    __shared__ int cur[512];
    __shared__ int buf[512];
    __shared__ int lcsr[CAP];

    const int t = threadIdx.x;
    const int b = blockIdx.x;
    const int s0 = b * CAP;
    const int n = cursor[b];             // fill level (cursor zero-based)

    cnts[t] = 0;
    __syncthreads();
    for (int i = t; i < n; i += 512)
        atomicAdd(&cnts[binned[s0 + i] & BMASK], 1);
    __syncthreads();

    {
        const int v = cnts[t];
        buf[t] = v; __syncthreads();
        for (int o = 1; o < 512; o <<= 1) {
            const int a = (t >= o) ? buf[t - o] : 0;
            __syncthreads();
            buf[t] += a;
            __syncthreads();
        }
        cur[t] = buf[t] - v;   // exclusive prefix
        const int node = (b << BSHIFT) + t;
        if (node < N_NODES) {
            row_start[node] = s0 + cur[t];
            row_cnt[node]   = (unsigned short)v;
        }
    }
    __syncthreads();

    for (int i = t; i < n; i += 512) {
        const int v = binned[s0 + i];
        const int p = atomicAdd(&cur[v & BMASK], 1);
        lcsr[p] = v >> BSHIFT;
    }
    __syncthreads();

    for (int i = t; i < n; i += 512) binned[s0 + i] = lcsr[i];
}

// ============================== Fused AGNN gather ===========================
// 16 lanes per dst node; lane l owns feature l. bf16 xn rows (32 B), gather
// set L2-resident. Software-pipelined: next batch's (sidx,row,norm) prefetched
// into registers while computing the current batch; dot split into 4 chains.
template <int EMIT_NORMED>
__global__ __launch_bounds__(256) void k_agnn(const int* __restrict__ row_start,
                                              const unsigned short* __restrict__ row_cnt,
                                              const int* __restrict__ csr_src,
                                              const unsigned short* __restrict__ xnb,
                                              const float* __restrict__ normv,
                                              const float* __restrict__ betap,
                                              float* __restrict__ outf,
                                              unsigned short* __restrict__ outb,
                                              float* __restrict__ out_norm) {
    const int l16  = threadIdx.x & 15;
    const int node = (blockIdx.x * 256 + threadIdx.x) >> 4;   // grid exact
    const float beta  = betap ? betap[0] : 1.0f;
    const float shift = fabsf(beta);

    const int rs  = row_start[node];
    const int cnt = row_cnt[node];

    // dst row: 2x16B bf16 loads -> 16 f32 regs
    const bf16x8* xd = (const bf16x8*)(xnb + (size_t)node * HID);
    const bf16x8 dlo = xd[0], dhi = xd[1];
    float dd[16];
#pragma unroll
    for (int i = 0; i < 8; i++) {
        dd[i]     = bf2f((unsigned short)dlo[i]);
        dd[i + 8] = bf2f((unsigned short)dhi[i]);
    }

    const unsigned short* colb = xnb + l16;   // lane's feature column base
    float acc0 = 0.f, acc1 = 0.f, sw = 0.f;

    // prologue: prefetch batch 0
    bool ok = (l16 < cnt);
    int sidx = ok ? csr_src[rs + l16] : 0;
    const bf16x8* xs0 = (const bf16x8*)(xnb + (size_t)sidx * HID);
    bf16x8 slo = xs0[0], shi = xs0[1];
    float nj = normv[sidx];

    for (int t = 0; t < cnt; t += 16) {
        // prefetch batch t+16
        const int k2 = t + 16 + l16;
        const bool ok2 = (k2 < cnt);
        const int sidx2 = ok2 ? csr_src[rs + k2] : 0;
        const bf16x8* xs2 = (const bf16x8*)(xnb + (size_t)sidx2 * HID);
        const bf16x8 slo2 = xs2[0], shi2 = xs2[1];
        const float nj2 = normv[sidx2];

        // compute current batch: dot as 4 independent chains
        float p0 = 0.f, p1 = 0.f, p2 = 0.f, p3 = 0.f;
#pragma unroll
        for (int i = 0; i < 4; i++) {
            p0 += bf2f((unsigned short)slo[i])     * dd[i];
            p1 += bf2f((unsigned short)slo[i + 4]) * dd[i + 4];
            p2 += bf2f((unsigned short)shi[i])     * dd[i + 8];
            p3 += bf2f((unsigned short)shi[i + 4]) * dd[i + 12];
        }
        const float dot = (p0 + p1) + (p2 + p3);
        const float w = ok ? __expf(beta * dot - shift) : 0.f;

        float ws = w;
        ws += __shfl_xor(ws, 1); ws += __shfl_xor(ws, 2);
        ws += __shfl_xor(ws, 4); ws += __shfl_xor(ws, 8);
        sw += ws;

        const float wn = w * nj;         // fold ||h_src|| into the weight
#pragma unroll
        for (int j = 0; j < 16; j += 2) {
            const float w0 = __shfl(wn, j, 16);
            const int   s0i = __shfl(sidx, j, 16);
            const float w1 = __shfl(wn, j + 1, 16);
            const int   s1i = __shfl(sidx, j + 1, 16);
            acc0 += w0 * bf2f(colb[(size_t)s0i * HID]);
            acc1 += w1 * bf2f(colb[(size_t)s1i * HID]);
        }

        sidx = sidx2; slo = slo2; shi = shi2; nj = nj2; ok = ok2;
    }

    const float v = (acc0 + acc1) / fmaxf(sw, 1e-16f);
    if (EMIT_NORMED) {
        float ss = v * v;
        ss += __shfl_xor(ss, 1); ss += __shfl_xor(ss, 2);
        ss += __shfl_xor(ss, 4); ss += __shfl_xor(ss, 8);
        const float nrm = sqrtf(ss);
        const float rn  = 1.f / fmaxf(nrm, 1e-12f);
        outb[(size_t)node * HID + l16] = f2bf_rtn(v * rn);
        if (l16 == 0) out_norm[node] = nrm;
    } else {
        outf[(size_t)node * HID + l16] = v;
    }
}

// ============================== Stage 3 =====================================
__global__ __launch_bounds__(256) void k_lin2(const float* __restrict__ h,
                                              const float* __restrict__ w2,
                                              const float* __restrict__ b2,
                                              float* __restrict__ out) {
    __shared__ float w2s[N_CLASS][HID];
    __shared__ float b2s[N_CLASS];
    for (int i = threadIdx.x; i < N_CLASS * HID; i += 256)
        ((float*)w2s)[i] = w2[i];
    if (threadIdx.x < N_CLASS) b2s[threadIdx.x] = b2[threadIdx.x];
    __syncthreads();

    const int n = blockIdx.x * 256 + threadIdx.x;
    if (n >= N_NODES) return;

    float hv[HID];
    const float4* hr = (const float4*)(h + (size_t)n * HID);
#pragma unroll
    for (int q = 0; q < 4; q++) {
        const float4 v = hr[q];
        hv[q*4+0]=v.x; hv[q*4+1]=v.y; hv[q*4+2]=v.z; hv[q*4+3]=v.w;
    }

    float lg[N_CLASS];
    float m = -3.0e38f;
#pragma unroll
    for (int j = 0; j < N_CLASS; j++) {
        float acc = b2s[j];
#pragma unroll
        for (int k = 0; k < HID; k++) acc += hv[k] * w2s[j][k];
        lg[j] = acc;
        m = fmaxf(m, acc);
    }
    float sum = 0.f;
#pragma unroll
    for (int j = 0; j < N_CLASS; j++) sum += __expf(lg[j] - m);
    const float lse = m + __logf(sum);

    float4* orow = (float4*)(out + (size_t)n * N_CLASS);
#pragma unroll
    for (int q = 0; q < N_CLASS / 4; q++) {
        float4 o;
        o.x = lg[q*4+0] - lse;
        o.y = lg[q*4+1] - lse;
        o.z = lg[q*4+2] - lse;
        o.w = lg[q*4+3] - lse;
        orow[q] = o;
    }
}

// ============================== Launch ======================================
extern "C" void kernel_launch(void* const* d_in, const int* in_sizes, int n_in,
                              void* d_out, int out_size, void* d_ws, size_t ws_size,
                              hipStream_t stream) {
    const float* x     = (const float*)d_in[0];
    const int*   ei    = (const int*)  d_in[1];   // [2][E]: row0=src, row1=dst
    const float* w1    = (const float*)d_in[2];
    const float* b1    = (const float*)d_in[3];
    const float* beta2 = (const float*)d_in[4];
    const float* w2    = (const float*)d_in[5];
    const float* b2    = (const float*)d_in[6];
    float* out = (float*)d_out;

    const int* srcp = ei;
    const int* dstp = ei + N_EDGES;

    // workspace layout (~28.8 MB)
    unsigned short* xnb1 = (unsigned short*)d_ws;        // [N,16] bf16 unit rows
    unsigned short* xnb2 = xnb1 + (size_t)N_NODES * HID; // [N,16] bf16
    float* norm1 = (float*)(xnb2 + (size_t)N_NODES * HID); // [N]
    float* norm2 = norm1 + N_NODES;                      // [N]
    float* hF    = norm2 + N_NODES;                      // [N,16] f32 final
    int* row_start = (int*)(hF + (size_t)N_NODES * HID); // [N]
    unsigned short* row_cnt = (unsigned short*)(row_start + N_NODES); // [N]
    int* cursor = (int*)(row_cnt + N_NODES + (N_NODES & 1)); // [NB]
    int* binned = cursor + NB + 2;                       // [NB*CAP] padded

    const int nodeGrid = (N_NODES + 255) / 256;        // 391
    const int agnnGrid = N_NODES * HID / 256;          // 6250

    // cursor := 0 (replaces k_init; memsetAsync is graph-capture-safe)
    hipMemsetAsync(cursor, 0, NB * sizeof(int), stream);

    // ---- fused CSR-binning + lin1 (independent pipelines, one dispatch) ----
    k_bin_lin1<<<BIN_BLOCKS + LIN1_BLOCKS, 256, 0, stream>>>(
        srcp, dstp, cursor, binned, x, w1, b1, xnb1, norm1);

    k_csr<<<NB, 512, 0, stream>>>(cursor, binned, row_start, row_cnt);

    // ---- AGNN layers (pipelined gather; norms fused into producers) ----
    k_agnn<1><<<agnnGrid, 256, 0, stream>>>(row_start, row_cnt, binned, xnb1,
                                            norm1, nullptr, nullptr, xnb2, norm2);
    k_agnn<0><<<agnnGrid, 256, 0, stream>>>(row_start, row_cnt, binned, xnb2,
                                            norm2, beta2, hF, nullptr, nullptr);

    k_lin2<<<nodeGrid, 256, 0, stream>>>(hF, w2, b2, out);
}